// Round 3
// baseline (742.951 us; speedup 1.0000x reference)
//
#include <hip/hip_runtime.h>

#define BB 4
#define NN 64
#define RR 8
#define DD 32
#define HH 96
#define EE 2
#define NGROUP (BB*NN*RR)   // 2048

// workspace float offsets
#define OFF_WR_R   0                      // nrWr row-major   [b][n][r][h]
#define OFF_WS_T   196608                 // nrWs transposed  [b][r][h][n]
#define OFF_NER0_R 393216
#define OFF_NES0_T 589824
#define OFF_NER1_R 786432
#define OFF_NES1_T 983040
#define OFF_ENC    1179648
#define OFF_AGG    1376256
#define OFF_W20T   1572864                // ep0_W2 transposed
#define OFF_W21T   1582080                // ep1_W2 transposed
#define OFF_EE0    1591296                // edge_effect step0, [g][k][j]
#define WS_FULL_FLOATS (OFF_EE0 + (size_t)NGROUP*HH*NN)

// ---------------------------------------------------------------------------
// K1: node encodings + projections; extra blocks transpose ep*_W2.
// ---------------------------------------------------------------------------
__global__ __launch_bounds__(64)
void k1_node(const float* __restrict__ node_rep,
             const float* __restrict__ ne_W, const float* __restrict__ ne_b,
             const float* __restrict__ ee_W,
             const float* __restrict__ ep0_W1,
             const float* __restrict__ ep0_W2, const float* __restrict__ ep1_W2,
             float* __restrict__ wr_r, float* __restrict__ ws_t,
             float* __restrict__ ner0_r, float* __restrict__ nes0_t,
             float* __restrict__ enc_out,
             float* __restrict__ w20t, float* __restrict__ w21t)
{
    int blk = blockIdx.x;
    int l = threadIdx.x;
    if (blk >= NGROUP) {
        int idx = blk - NGROUP;
        int mat = idx / HH;
        int c = idx % HH;
        const float* W2 = mat ? ep1_W2 : ep0_W2;
        float* Wt = (mat ? w21t : w20t) + c*HH;
        Wt[l] = W2[l*HH + c];
        if (l < 32) Wt[64+l] = W2[(64+l)*HH + c];
        return;
    }
    int b = blk >> 9, n = (blk >> 3) & 63, r = blk & 7;
    __shared__ float sX[DD];
    __shared__ float sEnc[HH];
    const float* x = node_rep + (size_t)blk * DD;
    if (l < DD) sX[l] = x[l];
    __syncthreads();

    float ne0 = ne_b[l], wr0 = 0.f, ws0 = 0.f;
    float ne1 = (l < 32) ? ne_b[64+l] : 0.f, wr1 = 0.f, ws1 = 0.f;
    #pragma unroll 4
    for (int k = 0; k < DD; k++) {
        float xv = sX[k];
        ne0 = fmaf(xv, ne_W[k*HH + l], ne0);
        wr0 = fmaf(xv, ee_W[k*HH + l], wr0);
        ws0 = fmaf(xv, ee_W[(DD+k)*HH + l], ws0);
        if (l < 32) {
            ne1 = fmaf(xv, ne_W[k*HH + 64+l], ne1);
            wr1 = fmaf(xv, ee_W[k*HH + 64+l], wr1);
            ws1 = fmaf(xv, ee_W[(DD+k)*HH + 64+l], ws1);
        }
    }
    ne0 = fmaxf(ne0, 0.f); ne1 = fmaxf(ne1, 0.f);
    float* enc  = enc_out + (size_t)blk*HH;
    float* wrr  = wr_r    + (size_t)blk*HH;
    float* wst  = ws_t    + (size_t)(b*RR + r)*HH*NN;
    enc[l] = ne0; wrr[l] = wr0; wst[l*NN + n] = ws0;
    sEnc[l] = ne0;
    if (l < 32) { enc[64+l] = ne1; wrr[64+l] = wr1; wst[(64+l)*NN + n] = ws1; sEnc[64+l] = ne1; }
    __syncthreads();

    const float* Er0 = ep0_W1;
    const float* Es0 = ep0_W1 + HH*HH;
    float er0 = 0.f, es0 = 0.f, er1 = 0.f, es1 = 0.f;
    #pragma unroll 4
    for (int k = 0; k < HH; k++) {
        float ev = sEnc[k];
        er0 = fmaf(ev, Er0[k*HH + l], er0);
        es0 = fmaf(ev, Es0[k*HH + l], es0);
        if (l < 32) {
            er1 = fmaf(ev, Er0[k*HH + 64+l], er1);
            es1 = fmaf(ev, Es0[k*HH + 64+l], es1);
        }
    }
    float* nerr = ner0_r + (size_t)blk*HH;
    float* nest = nes0_t + (size_t)(b*RR + r)*HH*NN;
    nerr[l] = er0; nest[l*NN + n] = es0;
    if (l < 32) { nerr[64+l] = er1; nest[(64+l)*NN + n] = es1; }
}

// ---------------------------------------------------------------------------
// K2: edge prop step 0. wave=(b,i,r), lane=j.
// Column-blocked GEMM: t[cb..cb+31] accumulators live across k; weights
// streamed as 32-float contiguous scalar chunks; activations reloaded per
// pass from L2 (no runtime-indexed register arrays).
// ---------------------------------------------------------------------------
template<bool STORE>
__global__ __launch_bounds__(64, 2)
void k2_edge0(const float* __restrict__ wr_r, const float* __restrict__ ws_t,
              const float* __restrict__ ner_r, const float* __restrict__ nes_t,
              const float* __restrict__ w20t,
              const float* __restrict__ ee_b,
              const float* __restrict__ ep0_W1, const float* __restrict__ ep0_b1,
              const float* __restrict__ ep0_b2,
              float* __restrict__ ee0_out, float* __restrict__ agg_out)
{
    int g = blockIdx.x;
    int j = threadIdx.x;
    int b = g >> 9, r = g & 7;
    const float* wr  = wr_r  + (size_t)g*HH;                 // uniform
    const float* ner = ner_r + (size_t)g*HH;                 // uniform
    const float* wst = ws_t  + (size_t)(b*RR + r)*HH*NN + j; // per-lane
    const float* nst = nes_t + (size_t)(b*RR + r)*HH*NN + j;
    const float* Ee0 = ep0_W1 + 2*HH*HH;

    float t[HH];
    #pragma unroll
    for (int c = 0; c < HH; c++) t[c] = ep0_b1[c] + ner[c] + nst[c*NN];

    // GEMM: t[c] += relu(wr_k + wst_k + b_k) * Ee0[k][c]
    #pragma unroll
    for (int cb = 0; cb < HH; cb += 32) {
        #pragma unroll 2
        for (int k = 0; k < HH; k++) {
            float a = fmaxf(wr[k] + wst[k*NN] + ee_b[k], 0.f);
            const float* w = Ee0 + k*HH + cb;
            #pragma unroll
            for (int i = 0; i < 32; i++) t[cb+i] = fmaf(a, w[i], t[cb+i]);
        }
    }
    #pragma unroll
    for (int c = 0; c < HH; c++) t[c] = fmaxf(t[c], 0.f);

    // ee0[c'] = relu(t . w20t[c'] + b2[c']); store + wave-sum for agg
    float aggA = 0.f, aggB = 0.f;
    float* eo = ee0_out + (size_t)g*HH*NN + j;
    #pragma unroll 2
    for (int c = 0; c < HH; c++) {
        const float* w = w20t + c*HH;
        float a0 = 0.f, a1 = 0.f, a2 = 0.f, a3 = 0.f;
        #pragma unroll
        for (int k = 0; k < HH; k += 4) {
            a0 = fmaf(t[k  ], w[k  ], a0);
            a1 = fmaf(t[k+1], w[k+1], a1);
            a2 = fmaf(t[k+2], w[k+2], a2);
            a3 = fmaf(t[k+3], w[k+3], a3);
        }
        float ee = fmaxf((a0+a1)+(a2+a3) + ep0_b2[c], 0.f);
        if (STORE) eo[c*NN] = ee;
        float s = ee;
        s += __shfl_xor(s, 1);
        s += __shfl_xor(s, 2);
        s += __shfl_xor(s, 4);
        s += __shfl_xor(s, 8);
        s += __shfl_xor(s, 16);
        s += __shfl_xor(s, 32);
        aggA = (c == j)      ? s : aggA;
        aggB = (c == 64 + j) ? s : aggB;
    }
    float* agg = agg_out + (size_t)g*HH;
    agg[j] = aggA;
    if (j < 32) agg[64 + j] = aggB;
}

// ---------------------------------------------------------------------------
// K3: node update after step 0 + step-1 projections. (unchanged)
// ---------------------------------------------------------------------------
__global__ __launch_bounds__(64)
void k3_node(const float* __restrict__ enc_in, const float* __restrict__ agg_in,
             const float* __restrict__ np_W1, const float* __restrict__ np_b1,
             const float* __restrict__ np_W2, const float* __restrict__ np_b2,
             const float* __restrict__ ep1_W1,
             float* __restrict__ ner1_r, float* __restrict__ nes1_t)
{
    int blk = blockIdx.x, l = threadIdx.x;
    int b = blk >> 9, n = (blk >> 3) & 63, r = blk & 7;
    __shared__ float sEnc[HH], sAgg[HH], sT[HH], sNE[HH];
    const float* enc = enc_in + (size_t)blk*HH;
    const float* agg = agg_in + (size_t)blk*HH;
    sEnc[l] = enc[l]; sAgg[l] = agg[l];
    if (l < 32) { sEnc[64+l] = enc[64+l]; sAgg[64+l] = agg[64+l]; }
    __syncthreads();

    const float* Wn1 = np_W1;
    const float* Wn2 = np_W1 + HH*HH;
    const float* Wn3 = np_W1 + 2*HH*HH;
    float t0 = np_b1[l], t1 = (l < 32) ? np_b1[64+l] : 0.f;
    #pragma unroll 4
    for (int k = 0; k < HH; k++) {
        float ev = sEnc[k], av = sAgg[k];
        t0 = fmaf(ev, Wn1[k*HH+l], t0);
        t0 = fmaf(ev, Wn2[k*HH+l], t0);
        t0 = fmaf(av, Wn3[k*HH+l], t0);
        if (l < 32) {
            t1 = fmaf(ev, Wn1[k*HH+64+l], t1);
            t1 = fmaf(ev, Wn2[k*HH+64+l], t1);
            t1 = fmaf(av, Wn3[k*HH+64+l], t1);
        }
    }
    sT[l] = fmaxf(t0, 0.f);
    if (l < 32) sT[64+l] = fmaxf(t1, 0.f);
    __syncthreads();

    float e0 = np_b2[l], e1 = (l < 32) ? np_b2[64+l] : 0.f;
    #pragma unroll 4
    for (int k = 0; k < HH; k++) {
        float tv = sT[k];
        e0 = fmaf(tv, np_W2[k*HH+l], e0);
        if (l < 32) e1 = fmaf(tv, np_W2[k*HH+64+l], e1);
    }
    sNE[l] = fmaxf(e0, 0.f);
    if (l < 32) sNE[64+l] = fmaxf(e1, 0.f);
    __syncthreads();

    const float* Er1 = ep1_W1;
    const float* Es1 = ep1_W1 + HH*HH;
    float er0 = 0.f, es0 = 0.f, er1v = 0.f, es1v = 0.f;
    #pragma unroll 4
    for (int k = 0; k < HH; k++) {
        float ev = sNE[k];
        er0 = fmaf(ev, Er1[k*HH+l], er0);
        es0 = fmaf(ev, Es1[k*HH+l], es0);
        if (l < 32) {
            er1v = fmaf(ev, Er1[k*HH+64+l], er1v);
            es1v = fmaf(ev, Es1[k*HH+64+l], es1v);
        }
    }
    float* nerr = ner1_r + (size_t)blk*HH;
    float* nest = nes1_t + (size_t)(b*RR + r)*HH*NN;
    nerr[l] = er0; nest[l*NN + n] = es0;
    if (l < 32) { nerr[64+l] = er1v; nest[(64+l)*NN + n] = es1v; }
}

// ---------------------------------------------------------------------------
// K4: edge prop step 1 fused with prediction head. wave=(b,i,r), lane=j.
// Column-blocked GEMMs; ee1 (and recomputed ee0 in non-FULL) staged through
// a 12 KB LDS buffer in k-halves (same-lane dependency, no barrier needed).
// ---------------------------------------------------------------------------
template<bool FULL>
__global__ __launch_bounds__(64, 2)
void k4_edge1(const float* __restrict__ wr_r, const float* __restrict__ ws_t,
              const float* __restrict__ ner1_rp, const float* __restrict__ nes1_tp,
              const float* __restrict__ ner0_rp, const float* __restrict__ nes0_tp,
              const float* __restrict__ w20t, const float* __restrict__ w21t,
              const float* __restrict__ ee0_in,
              const float* __restrict__ ee_b,
              const float* __restrict__ ep0_W1, const float* __restrict__ ep0_b1, const float* __restrict__ ep0_b2,
              const float* __restrict__ ep1_W1, const float* __restrict__ ep1_b1, const float* __restrict__ ep1_b2,
              const float* __restrict__ pred_W1, const float* __restrict__ pred_b1,
              const float* __restrict__ pred_W2, const float* __restrict__ pred_b2,
              float* __restrict__ out)
{
    int g = blockIdx.x, j = threadIdx.x;
    int b = g >> 9, i = (g >> 3) & 63, r = g & 7;
    const float* wr   = wr_r    + (size_t)g*HH;
    const float* wst  = ws_t    + (size_t)(b*RR + r)*HH*NN + j;
    const float* ner1 = ner1_rp + (size_t)g*HH;
    const float* nes1 = nes1_tp + (size_t)(b*RR + r)*HH*NN + j;
    const float* Ee1  = ep1_W1 + 2*HH*HH;
    const float* Pe   = pred_W1;
    const float* Pc   = pred_W1 + HH*HH;

    __shared__ float s_e[48*64];   // 12 KB k-half staging

    float t1[HH];
    #pragma unroll
    for (int c = 0; c < HH; c++) t1[c] = ep1_b1[c] + ner1[c] + nes1[c*NN];

    if (FULL) {
        // t1 += ee0 @ Ee1, ee0 read from global per pass (L2-resident slab)
        const float* e0 = ee0_in + (size_t)g*HH*NN + j;
        #pragma unroll
        for (int cb = 0; cb < HH; cb += 32) {
            #pragma unroll 2
            for (int k = 0; k < HH; k++) {
                float a = e0[k*NN];
                const float* w = Ee1 + k*HH + cb;
                #pragma unroll
                for (int ii = 0; ii < 32; ii++) t1[cb+ii] = fmaf(a, w[ii], t1[cb+ii]);
            }
        }
    } else {
        // recompute ee0: t0 GEMM, then dot rows of w20t, staged via LDS
        float t0[HH];
        const float* ner0 = ner0_rp + (size_t)g*HH;
        const float* nes0 = nes0_tp + (size_t)(b*RR + r)*HH*NN + j;
        const float* Ee0  = ep0_W1 + 2*HH*HH;
        #pragma unroll
        for (int c = 0; c < HH; c++) t0[c] = ep0_b1[c] + ner0[c] + nes0[c*NN];
        #pragma unroll
        for (int cb = 0; cb < HH; cb += 32) {
            #pragma unroll 2
            for (int k = 0; k < HH; k++) {
                float a = fmaxf(wr[k] + wst[k*NN] + ee_b[k], 0.f);
                const float* w = Ee0 + k*HH + cb;
                #pragma unroll
                for (int ii = 0; ii < 32; ii++) t0[cb+ii] = fmaf(a, w[ii], t0[cb+ii]);
            }
        }
        #pragma unroll
        for (int c = 0; c < HH; c++) t0[c] = fmaxf(t0[c], 0.f);

        #pragma unroll
        for (int kh = 0; kh < 2; kh++) {
            for (int kk = 0; kk < 48; kk++) {
                int k = kh*48 + kk;
                const float* w = w20t + k*HH;
                float a0=0.f,a1=0.f,a2=0.f,a3=0.f;
                #pragma unroll
                for (int m = 0; m < HH; m += 4) {
                    a0 = fmaf(t0[m  ], w[m  ], a0);
                    a1 = fmaf(t0[m+1], w[m+1], a1);
                    a2 = fmaf(t0[m+2], w[m+2], a2);
                    a3 = fmaf(t0[m+3], w[m+3], a3);
                }
                s_e[kk*64 + j] = fmaxf((a0+a1)+(a2+a3) + ep0_b2[k], 0.f);
            }
            #pragma unroll
            for (int cb = 0; cb < HH; cb += 32) {
                #pragma unroll 2
                for (int kk = 0; kk < 48; kk++) {
                    float a = s_e[kk*64 + j];
                    const float* w = Ee1 + (kh*48+kk)*HH + cb;
                    #pragma unroll
                    for (int ii = 0; ii < 32; ii++) t1[cb+ii] = fmaf(a, w[ii], t1[cb+ii]);
                }
            }
        }
    }
    #pragma unroll
    for (int c = 0; c < HH; c++) t1[c] = fmaxf(t1[c], 0.f);

    // tp = pred_b1 + edge_enc @ Pc  (edge_enc recomputed per pass)
    float tp[HH];
    #pragma unroll
    for (int c = 0; c < HH; c++) tp[c] = pred_b1[c];
    #pragma unroll
    for (int cb = 0; cb < HH; cb += 32) {
        #pragma unroll 2
        for (int k = 0; k < HH; k++) {
            float a = fmaxf(wr[k] + wst[k*NN] + ee_b[k], 0.f);
            const float* w = Pc + k*HH + cb;
            #pragma unroll
            for (int ii = 0; ii < 32; ii++) tp[cb+ii] = fmaf(a, w[ii], tp[cb+ii]);
        }
    }

    // tp += ee1 @ Pe;  ee1_k = relu(t1 . w21t[k] + b2[k]), staged via LDS
    #pragma unroll
    for (int kh = 0; kh < 2; kh++) {
        for (int kk = 0; kk < 48; kk++) {
            int k = kh*48 + kk;
            const float* w = w21t + k*HH;
            float a0=0.f,a1=0.f,a2=0.f,a3=0.f;
            #pragma unroll
            for (int m = 0; m < HH; m += 4) {
                a0 = fmaf(t1[m  ], w[m  ], a0);
                a1 = fmaf(t1[m+1], w[m+1], a1);
                a2 = fmaf(t1[m+2], w[m+2], a2);
                a3 = fmaf(t1[m+3], w[m+3], a3);
            }
            s_e[kk*64 + j] = fmaxf((a0+a1)+(a2+a3) + ep1_b2[k], 0.f);
        }
        #pragma unroll
        for (int cb = 0; cb < HH; cb += 32) {
            #pragma unroll 2
            for (int kk = 0; kk < 48; kk++) {
                float a = s_e[kk*64 + j];
                const float* w = Pe + (kh*48+kk)*HH + cb;
                #pragma unroll
                for (int ii = 0; ii < 32; ii++) tp[cb+ii] = fmaf(a, w[ii], tp[cb+ii]);
            }
        }
    }

    float o0 = pred_b2[0], o1 = pred_b2[1];
    #pragma unroll
    for (int c = 0; c < HH; c++) {
        float tpc = fmaxf(tp[c], 0.f);
        o0 = fmaf(tpc, pred_W2[c*EE    ], o0);
        o1 = fmaf(tpc, pred_W2[c*EE + 1], o1);
    }
    float2* out2 = (float2*)out;
    out2[((size_t)(b*NN + i)*NN + j)*RR + r] = make_float2(o0, o1);
}

// ---------------------------------------------------------------------------
extern "C" void kernel_launch(void* const* d_in, const int* in_sizes, int n_in,
                              void* d_out, int out_size, void* d_ws, size_t ws_size,
                              hipStream_t stream)
{
    const float* node_rep = (const float*)d_in[0];
    const float* ne_W    = (const float*)d_in[1];
    const float* ne_b    = (const float*)d_in[2];
    const float* ee_W    = (const float*)d_in[3];
    const float* ee_b    = (const float*)d_in[4];
    const float* np_W1   = (const float*)d_in[5];
    const float* np_b1   = (const float*)d_in[6];
    const float* np_W2   = (const float*)d_in[7];
    const float* np_b2   = (const float*)d_in[8];
    const float* ep0_W1  = (const float*)d_in[9];
    const float* ep0_b1  = (const float*)d_in[10];
    const float* ep0_W2  = (const float*)d_in[11];
    const float* ep0_b2  = (const float*)d_in[12];
    const float* ep1_W1  = (const float*)d_in[13];
    const float* ep1_b1  = (const float*)d_in[14];
    const float* ep1_W2  = (const float*)d_in[15];
    const float* ep1_b2  = (const float*)d_in[16];
    const float* pred_W1 = (const float*)d_in[17];
    const float* pred_b1 = (const float*)d_in[18];
    const float* pred_W2 = (const float*)d_in[19];
    const float* pred_b2 = (const float*)d_in[20];
    float* wsf = (float*)d_ws;
    float* out = (float*)d_out;

    float* wr_r   = wsf + OFF_WR_R;
    float* ws_t   = wsf + OFF_WS_T;
    float* ner0_r = wsf + OFF_NER0_R;
    float* nes0_t = wsf + OFF_NES0_T;
    float* ner1_r = wsf + OFF_NER1_R;
    float* nes1_t = wsf + OFF_NES1_T;
    float* enc    = wsf + OFF_ENC;
    float* agg    = wsf + OFF_AGG;
    float* w20t   = wsf + OFF_W20T;
    float* w21t   = wsf + OFF_W21T;
    float* ee0    = wsf + OFF_EE0;

    bool full = ws_size >= WS_FULL_FLOATS * sizeof(float);

    k1_node<<<NGROUP + 2*HH, 64, 0, stream>>>(node_rep, ne_W, ne_b, ee_W, ep0_W1,
                                              ep0_W2, ep1_W2,
                                              wr_r, ws_t, ner0_r, nes0_t, enc, w20t, w21t);
    if (full)
        k2_edge0<true><<<NGROUP, 64, 0, stream>>>(wr_r, ws_t, ner0_r, nes0_t, w20t,
                                                  ee_b, ep0_W1, ep0_b1, ep0_b2, ee0, agg);
    else
        k2_edge0<false><<<NGROUP, 64, 0, stream>>>(wr_r, ws_t, ner0_r, nes0_t, w20t,
                                                   ee_b, ep0_W1, ep0_b1, ep0_b2, ee0, agg);

    k3_node<<<NGROUP, 64, 0, stream>>>(enc, agg, np_W1, np_b1, np_W2, np_b2,
                                       ep1_W1, ner1_r, nes1_t);

    if (full)
        k4_edge1<true><<<NGROUP, 64, 0, stream>>>(wr_r, ws_t, ner1_r, nes1_t, ner0_r, nes0_t,
                                                  w20t, w21t, ee0, ee_b,
                                                  ep0_W1, ep0_b1, ep0_b2,
                                                  ep1_W1, ep1_b1, ep1_b2,
                                                  pred_W1, pred_b1, pred_W2, pred_b2, out);
    else
        k4_edge1<false><<<NGROUP, 64, 0, stream>>>(wr_r, ws_t, ner1_r, nes1_t, ner0_r, nes0_t,
                                                   w20t, w21t, ee0, ee_b,
                                                   ep0_W1, ep0_b1, ep0_b2,
                                                   ep1_W1, ep1_b1, ep1_b2,
                                                   pred_W1, pred_b1, pred_W2, pred_b2, out);
}

// Round 4
// 186.984 us; speedup vs baseline: 3.9733x; 3.9733x over previous
//
#include <hip/hip_runtime.h>
#include <hip/hip_bf16.h>

#define BB 4
#define NN 64
#define RR 8
#define DD 32
#define HH 96
#define NGROUP (BB*NN*RR)   // 2048

// float offsets in workspace
#define OFF_WR    0                       // wr' = node@Wr + ee_b      [g][96]
#define OFF_WS_T  196608                  // ws proj transposed        [b*8+r][96][64]
#define OFF_NER0  393216                  // ner0' = enc@Er0 + ep0_b1  [g][96]
#define OFF_NES0  589824                  // [b*8+r][96][64]
#define OFF_NER1  786432                  // ner1' = ne1@Er1 + ep1_b1
#define OFF_NES1  983040
#define OFF_ENC   1179648
#define OFF_AGG   1376256
#define OFF_PKW   1572864                 // packed bf16 weight frags: 6*4608 + 768 dwords
#define OFF_EE0F  1601280                 // ee0 in B-frag form: 2048*3072 dwords

typedef __attribute__((ext_vector_type(4))) float f32x4;
typedef __attribute__((ext_vector_type(8))) short bf16x8;
typedef __attribute__((ext_vector_type(4))) unsigned int u32x4;

__device__ __forceinline__ unsigned int pk2(float lo, float hi){
    unsigned short a = __builtin_bit_cast(unsigned short, __float2bfloat16(lo));
    unsigned short b = __builtin_bit_cast(unsigned short, __float2bfloat16(hi));
    return (unsigned)a | ((unsigned)b << 16);
}

#define MFMA16(A,B,C) __builtin_amdgcn_mfma_f32_16x16x32_bf16((A),(B),(C),0,0,0)

// ---------------------------------------------------------------------------
// K1: node encodings + fp32 projections (biases folded) + bf16 weight packing.
// grid: NGROUP + 111 blocks of 64.
// Packed A-frag layout (transposed-space A = W^T):
//   frag(mt,kb): lane l, dword p holds bf16 pair W[k][16mt+(l&15)], k=32kb+8(l>>4)+2p(+1)
// ---------------------------------------------------------------------------
__global__ __launch_bounds__(64)
void k1_node(const float* __restrict__ node_rep,
             const float* __restrict__ ne_W, const float* __restrict__ ne_b,
             const float* __restrict__ ee_W, const float* __restrict__ ee_b,
             const float* __restrict__ ep0_W1, const float* __restrict__ ep0_b1,
             const float* __restrict__ ep0_W2,
             const float* __restrict__ ep1_W1, const float* __restrict__ ep1_W2,
             const float* __restrict__ pred_W1, const float* __restrict__ pred_W2,
             float* __restrict__ wr_r, float* __restrict__ ws_t,
             float* __restrict__ ner0, float* __restrict__ nes0,
             float* __restrict__ enc_out, unsigned int* __restrict__ pk_w)
{
    int blk = blockIdx.x;
    int l = threadIdx.x;
    if (blk >= NGROUP) {                       // weight packing blocks
        int t = blk - NGROUP;                  // 0..110
        int cL = l & 15, gq = l >> 4;
        if (t < 108) {
            int mat = t / 18, tt = t % 18, mt = tt / 3, kb = tt % 3;
            const float* mats[6] = { ep0_W1 + 2*HH*HH, ep0_W2, ep1_W1 + 2*HH*HH,
                                     ep1_W2, pred_W1, pred_W1 + HH*HH };
            const float* src = mats[mat];
            u32x4 d;
            #pragma unroll
            for (int p = 0; p < 4; p++) {
                int k = 32*kb + 8*gq + 2*p;
                d[p] = pk2(src[k*HH + 16*mt + cL], src[(k+1)*HH + 16*mt + cL]);
            }
            *(u32x4*)&pk_w[mat*4608 + (mt*3+kb)*256 + l*4] = d;
        } else {                               // pred_W2 [96][2], zero-padded to 16 rows
            int kb = t - 108;
            u32x4 d;
            #pragma unroll
            for (int p = 0; p < 4; p++) {
                int k = 32*kb + 8*gq + 2*p;
                float lo = (cL < 2) ? pred_W2[k*2 + cL]     : 0.f;
                float hi = (cL < 2) ? pred_W2[(k+1)*2 + cL] : 0.f;
                d[p] = pk2(lo, hi);
            }
            *(u32x4*)&pk_w[6*4608 + kb*256 + l*4] = d;
        }
        return;
    }
    int b = blk >> 9, n = (blk >> 3) & 63, r = blk & 7;
    __shared__ float sX[DD];
    __shared__ float sEnc[HH];
    const float* x = node_rep + (size_t)blk * DD;
    if (l < DD) sX[l] = x[l];
    __syncthreads();

    float ne0 = ne_b[l], wr0 = 0.f, ws0 = 0.f;
    float ne1 = (l < 32) ? ne_b[64+l] : 0.f, wr1 = 0.f, ws1 = 0.f;
    #pragma unroll 4
    for (int k = 0; k < DD; k++) {
        float xv = sX[k];
        ne0 = fmaf(xv, ne_W[k*HH + l], ne0);
        wr0 = fmaf(xv, ee_W[k*HH + l], wr0);
        ws0 = fmaf(xv, ee_W[(DD+k)*HH + l], ws0);
        if (l < 32) {
            ne1 = fmaf(xv, ne_W[k*HH + 64+l], ne1);
            wr1 = fmaf(xv, ee_W[k*HH + 64+l], wr1);
            ws1 = fmaf(xv, ee_W[(DD+k)*HH + 64+l], ws1);
        }
    }
    ne0 = fmaxf(ne0, 0.f); ne1 = fmaxf(ne1, 0.f);
    float* enc  = enc_out + (size_t)blk*HH;
    float* wrr  = wr_r    + (size_t)blk*HH;
    float* wst  = ws_t    + (size_t)(b*RR + r)*HH*NN;
    enc[l] = ne0; wrr[l] = wr0 + ee_b[l]; wst[l*NN + n] = ws0;
    sEnc[l] = ne0;
    if (l < 32) { enc[64+l] = ne1; wrr[64+l] = wr1 + ee_b[64+l]; wst[(64+l)*NN + n] = ws1; sEnc[64+l] = ne1; }
    __syncthreads();

    const float* Er0 = ep0_W1;
    const float* Es0 = ep0_W1 + HH*HH;
    float er0 = 0.f, es0 = 0.f, er1 = 0.f, es1 = 0.f;
    #pragma unroll 4
    for (int k = 0; k < HH; k++) {
        float ev = sEnc[k];
        er0 = fmaf(ev, Er0[k*HH + l], er0);
        es0 = fmaf(ev, Es0[k*HH + l], es0);
        if (l < 32) {
            er1 = fmaf(ev, Er0[k*HH + 64+l], er1);
            es1 = fmaf(ev, Es0[k*HH + 64+l], es1);
        }
    }
    float* nerr = ner0 + (size_t)blk*HH;
    float* nest = nes0 + (size_t)(b*RR + r)*HH*NN;
    nerr[l] = er0 + ep0_b1[l]; nest[l*NN + n] = es0;
    if (l < 32) { nerr[64+l] = er1 + ep0_b1[64+l]; nest[(64+l)*NN + n] = es1; }
}

// ---------------------------------------------------------------------------
// K2: edge prop step 0 via MFMA. 1 wave per g=(b,i,r); transposed space:
// D[c][j] tiles, A = packed W^T frags, B = activations^T frags.
// ---------------------------------------------------------------------------
__global__ __launch_bounds__(64)
void k2_edge0(const float* __restrict__ wr_r, const float* __restrict__ ws_t,
              const float* __restrict__ ner0, const float* __restrict__ nes0,
              const unsigned int* __restrict__ pk_w,
              const float* __restrict__ ep0_b2,
              unsigned int* __restrict__ ee0f, float* __restrict__ agg_out)
{
    int g = blockIdx.x, l = threadIdx.x;
    int b = g >> 9, r = g & 7;
    int cL = l & 15, gq = l >> 4;
    const float* wr  = wr_r + (size_t)g*HH;
    const float* wst = ws_t + (size_t)(b*RR+r)*HH*NN;
    const float* nrp = ner0 + (size_t)g*HH;
    const float* nsp = nes0 + (size_t)(b*RR+r)*HH*NN;
    const u32x4* Ae = (const u32x4*)(pk_w + 0*4608);   // Ee0 packed
    const u32x4* Aw = (const u32x4*)(pk_w + 1*4608);   // W20 packed
    __shared__ __align__(16) unsigned int sB[3072];

    // build edge_enc B-frags: ee[kb][n], element (gq,e): h=32kb+8gq+e, j=16n+cL
    u32x4 ee[3][4];
    #pragma unroll
    for (int kb = 0; kb < 3; kb++)
      #pragma unroll
      for (int n = 0; n < 4; n++)
        #pragma unroll
        for (int p = 0; p < 4; p++) {
            int h = 32*kb + 8*gq + 2*p;
            int j = 16*n + cL;
            float a0 = fmaxf(wr[h]   + wst[h*NN + j],     0.f);
            float a1 = fmaxf(wr[h+1] + wst[(h+1)*NN + j], 0.f);
            ee[kb][n][p] = pk2(a0, a1);
        }

    // C init: ner0' (b1 folded) + nes0
    f32x4 acc[6][4];
    #pragma unroll
    for (int m = 0; m < 6; m++)
      #pragma unroll
      for (int q = 0; q < 4; q++) {
        int c = 16*m + 4*gq + q;
        float nr = nrp[c];
        #pragma unroll
        for (int n = 0; n < 4; n++)
            acc[m][n][q] = nr + nsp[c*NN + 16*n + cL];
      }

    // GEMM1: t0^T = Ee0^T @ EE^T
    #pragma unroll
    for (int kb = 0; kb < 3; kb++) {
        bf16x8 A[6];
        #pragma unroll
        for (int m = 0; m < 6; m++) A[m] = __builtin_bit_cast(bf16x8, Ae[(m*3+kb)*64 + l]);
        #pragma unroll
        for (int n = 0; n < 4; n++) {
            bf16x8 Bf = __builtin_bit_cast(bf16x8, ee[kb][n]);
            #pragma unroll
            for (int m = 0; m < 6; m++) acc[m][n] = MFMA16(A[m], Bf, acc[m][n]);
        }
    }

    // relu + repack D -> B-frag layout in LDS (single wave, no barrier)
    #pragma unroll
    for (int m = 0; m < 6; m++)
      #pragma unroll
      for (int n = 0; n < 4; n++) {
        float v0 = fmaxf(acc[m][n][0],0.f), v1 = fmaxf(acc[m][n][1],0.f);
        float v2 = fmaxf(acc[m][n][2],0.f), v3 = fmaxf(acc[m][n][3],0.f);
        int gd = 2*(m&1) + (gq>>1);
        int dw = (((m>>1)*4 + n)*64 + 16*gd + cL)*4 + 2*(gq&1);
        sB[dw]   = pk2(v0,v1);
        sB[dw+1] = pk2(v2,v3);
      }

    // C init 2: ep0_b2
    #pragma unroll
    for (int m = 0; m < 6; m++)
      #pragma unroll
      for (int q = 0; q < 4; q++) {
        float bv = ep0_b2[16*m + 4*gq + q];
        #pragma unroll
        for (int n = 0; n < 4; n++) acc[m][n][q] = bv;
      }

    // GEMM2: ee0^T = W20^T @ t0^T
    #pragma unroll
    for (int kb = 0; kb < 3; kb++) {
        bf16x8 A[6];
        #pragma unroll
        for (int m = 0; m < 6; m++) A[m] = __builtin_bit_cast(bf16x8, Aw[(m*3+kb)*64 + l]);
        #pragma unroll
        for (int n = 0; n < 4; n++) {
            bf16x8 Bf = __builtin_bit_cast(bf16x8, *(const u32x4*)&sB[((kb*4+n)*64 + l)*4]);
            #pragma unroll
            for (int m = 0; m < 6; m++) acc[m][n] = MFMA16(A[m], Bf, acc[m][n]);
        }
    }

    // relu in place; agg reduce; pack+store ee0 frags (B-layout) to global
    #pragma unroll
    for (int m = 0; m < 6; m++)
      #pragma unroll
      for (int n = 0; n < 4; n++)
        #pragma unroll
        for (int q = 0; q < 4; q++) acc[m][n][q] = fmaxf(acc[m][n][q], 0.f);

    unsigned int* eo = ee0f + (size_t)g*3072;
    #pragma unroll
    for (int m = 0; m < 6; m++)
      #pragma unroll
      for (int n = 0; n < 4; n++) {
        int gd = 2*(m&1) + (gq>>1);
        int dw = (((m>>1)*4 + n)*64 + 16*gd + cL)*4 + 2*(gq&1);
        eo[dw]   = pk2(acc[m][n][0], acc[m][n][1]);
        eo[dw+1] = pk2(acc[m][n][2], acc[m][n][3]);
      }
    #pragma unroll
    for (int m = 0; m < 6; m++)
      #pragma unroll
      for (int q = 0; q < 4; q++) {
        float s = acc[m][0][q] + acc[m][1][q] + acc[m][2][q] + acc[m][3][q];
        s += __shfl_xor(s, 1);
        s += __shfl_xor(s, 2);
        s += __shfl_xor(s, 4);
        s += __shfl_xor(s, 8);
        if (cL == 0) agg_out[(size_t)g*HH + 16*m + 4*gq + q] = s;
      }
}

// ---------------------------------------------------------------------------
// K3: node update after step 0 + step-1 projections (fp32, ep1_b1 folded).
// ---------------------------------------------------------------------------
__global__ __launch_bounds__(64)
void k3_node(const float* __restrict__ enc_in, const float* __restrict__ agg_in,
             const float* __restrict__ np_W1, const float* __restrict__ np_b1,
             const float* __restrict__ np_W2, const float* __restrict__ np_b2,
             const float* __restrict__ ep1_W1, const float* __restrict__ ep1_b1,
             float* __restrict__ ner1, float* __restrict__ nes1)
{
    int blk = blockIdx.x, l = threadIdx.x;
    int b = blk >> 9, n = (blk >> 3) & 63, r = blk & 7;
    __shared__ float sEnc[HH], sAgg[HH], sT[HH], sNE[HH];
    const float* enc = enc_in + (size_t)blk*HH;
    const float* agg = agg_in + (size_t)blk*HH;
    sEnc[l] = enc[l]; sAgg[l] = agg[l];
    if (l < 32) { sEnc[64+l] = enc[64+l]; sAgg[64+l] = agg[64+l]; }
    __syncthreads();

    const float* Wn1 = np_W1;
    const float* Wn2 = np_W1 + HH*HH;
    const float* Wn3 = np_W1 + 2*HH*HH;
    float t0 = np_b1[l], t1 = (l < 32) ? np_b1[64+l] : 0.f;
    #pragma unroll 4
    for (int k = 0; k < HH; k++) {
        float ev = sEnc[k], av = sAgg[k];
        t0 = fmaf(ev, Wn1[k*HH+l], t0);
        t0 = fmaf(ev, Wn2[k*HH+l], t0);
        t0 = fmaf(av, Wn3[k*HH+l], t0);
        if (l < 32) {
            t1 = fmaf(ev, Wn1[k*HH+64+l], t1);
            t1 = fmaf(ev, Wn2[k*HH+64+l], t1);
            t1 = fmaf(av, Wn3[k*HH+64+l], t1);
        }
    }
    sT[l] = fmaxf(t0, 0.f);
    if (l < 32) sT[64+l] = fmaxf(t1, 0.f);
    __syncthreads();

    float e0 = np_b2[l], e1 = (l < 32) ? np_b2[64+l] : 0.f;
    #pragma unroll 4
    for (int k = 0; k < HH; k++) {
        float tv = sT[k];
        e0 = fmaf(tv, np_W2[k*HH+l], e0);
        if (l < 32) e1 = fmaf(tv, np_W2[k*HH+64+l], e1);
    }
    sNE[l] = fmaxf(e0, 0.f);
    if (l < 32) sNE[64+l] = fmaxf(e1, 0.f);
    __syncthreads();

    const float* Er1 = ep1_W1;
    const float* Es1 = ep1_W1 + HH*HH;
    float er0 = 0.f, es0 = 0.f, er1v = 0.f, es1v = 0.f;
    #pragma unroll 4
    for (int k = 0; k < HH; k++) {
        float ev = sNE[k];
        er0 = fmaf(ev, Er1[k*HH+l], er0);
        es0 = fmaf(ev, Es1[k*HH+l], es0);
        if (l < 32) {
            er1v = fmaf(ev, Er1[k*HH+64+l], er1v);
            es1v = fmaf(ev, Es1[k*HH+64+l], es1v);
        }
    }
    float* nerr = ner1 + (size_t)blk*HH;
    float* nest = nes1 + (size_t)(b*RR + r)*HH*NN;
    nerr[l] = er0 + ep1_b1[l]; nest[l*NN + n] = es0;
    if (l < 32) { nerr[64+l] = er1v + ep1_b1[64+l]; nest[(64+l)*NN + n] = es1v; }
}

// ---------------------------------------------------------------------------
// K4: edge prop step 1 + prediction head via MFMA. 1 wave per g.
// ---------------------------------------------------------------------------
__global__ __launch_bounds__(64)
void k4_edge1(const float* __restrict__ wr_r, const float* __restrict__ ws_t,
              const float* __restrict__ ner1, const float* __restrict__ nes1,
              const unsigned int* __restrict__ pk_w,
              const unsigned int* __restrict__ ee0f,
              const float* __restrict__ ep1_b2,
              const float* __restrict__ pred_b1, const float* __restrict__ pred_b2,
              float* __restrict__ out)
{
    int g = blockIdx.x, l = threadIdx.x;
    int b = g >> 9, i = (g >> 3) & 63, r = g & 7;
    int cL = l & 15, gq = l >> 4;
    const float* wr  = wr_r + (size_t)g*HH;
    const float* wst = ws_t + (size_t)(b*RR+r)*HH*NN;
    const float* nrp = ner1 + (size_t)g*HH;
    const float* nsp = nes1 + (size_t)(b*RR+r)*HH*NN;
    const u32x4* Ae1 = (const u32x4*)(pk_w + 2*4608);  // Ee1
    const u32x4* Aw1 = (const u32x4*)(pk_w + 3*4608);  // W21
    const u32x4* Ape = (const u32x4*)(pk_w + 4*4608);  // Pe
    const u32x4* Apc = (const u32x4*)(pk_w + 5*4608);  // Pc
    const u32x4* Ap2 = (const u32x4*)(pk_w + 6*4608);  // P2 padded
    __shared__ __align__(16) unsigned int sB[3072];

    // load ee0 B-frags
    const u32x4* e0p = (const u32x4*)ee0f + (size_t)g*768;
    u32x4 bf0[3][4];
    #pragma unroll
    for (int kb = 0; kb < 3; kb++)
      #pragma unroll
      for (int n = 0; n < 4; n++) bf0[kb][n] = e0p[(kb*4+n)*64 + l];

    // C init: ner1' + nes1
    f32x4 acc[6][4];
    #pragma unroll
    for (int m = 0; m < 6; m++)
      #pragma unroll
      for (int q = 0; q < 4; q++) {
        int c = 16*m + 4*gq + q;
        float nr = nrp[c];
        #pragma unroll
        for (int n = 0; n < 4; n++)
            acc[m][n][q] = nr + nsp[c*NN + 16*n + cL];
      }

    // GEMM1: t1^T = Ee1^T @ ee0^T
    #pragma unroll
    for (int kb = 0; kb < 3; kb++) {
        bf16x8 A[6];
        #pragma unroll
        for (int m = 0; m < 6; m++) A[m] = __builtin_bit_cast(bf16x8, Ae1[(m*3+kb)*64 + l]);
        #pragma unroll
        for (int n = 0; n < 4; n++) {
            bf16x8 Bf = __builtin_bit_cast(bf16x8, bf0[kb][n]);
            #pragma unroll
            for (int m = 0; m < 6; m++) acc[m][n] = MFMA16(A[m], Bf, acc[m][n]);
        }
    }

    // relu + repack t1 -> LDS B-frags
    #pragma unroll
    for (int m = 0; m < 6; m++)
      #pragma unroll
      for (int n = 0; n < 4; n++) {
        float v0 = fmaxf(acc[m][n][0],0.f), v1 = fmaxf(acc[m][n][1],0.f);
        float v2 = fmaxf(acc[m][n][2],0.f), v3 = fmaxf(acc[m][n][3],0.f);
        int gd = 2*(m&1) + (gq>>1);
        int dw = (((m>>1)*4 + n)*64 + 16*gd + cL)*4 + 2*(gq&1);
        sB[dw]   = pk2(v0,v1);
        sB[dw+1] = pk2(v2,v3);
      }

    // C init: ep1_b2
    #pragma unroll
    for (int m = 0; m < 6; m++)
      #pragma unroll
      for (int q = 0; q < 4; q++) {
        float bv = ep1_b2[16*m + 4*gq + q];
        #pragma unroll
        for (int n = 0; n < 4; n++) acc[m][n][q] = bv;
      }

    // GEMM2: ee1^T = W21^T @ t1^T
    #pragma unroll
    for (int kb = 0; kb < 3; kb++) {
        bf16x8 A[6];
        #pragma unroll
        for (int m = 0; m < 6; m++) A[m] = __builtin_bit_cast(bf16x8, Aw1[(m*3+kb)*64 + l]);
        #pragma unroll
        for (int n = 0; n < 4; n++) {
            bf16x8 Bf = __builtin_bit_cast(bf16x8, *(const u32x4*)&sB[((kb*4+n)*64 + l)*4]);
            #pragma unroll
            for (int m = 0; m < 6; m++) acc[m][n] = MFMA16(A[m], Bf, acc[m][n]);
        }
    }

    // relu + repack ee1 -> LDS B-frags (overwrites t1 frags)
    #pragma unroll
    for (int m = 0; m < 6; m++)
      #pragma unroll
      for (int n = 0; n < 4; n++) {
        float v0 = fmaxf(acc[m][n][0],0.f), v1 = fmaxf(acc[m][n][1],0.f);
        float v2 = fmaxf(acc[m][n][2],0.f), v3 = fmaxf(acc[m][n][3],0.f);
        int gd = 2*(m&1) + (gq>>1);
        int dw = (((m>>1)*4 + n)*64 + 16*gd + cL)*4 + 2*(gq&1);
        sB[dw]   = pk2(v0,v1);
        sB[dw+1] = pk2(v2,v3);
      }

    // C init: pred_b1
    #pragma unroll
    for (int m = 0; m < 6; m++)
      #pragma unroll
      for (int q = 0; q < 4; q++) {
        float bv = pred_b1[16*m + 4*gq + q];
        #pragma unroll
        for (int n = 0; n < 4; n++) acc[m][n][q] = bv;
      }

    // GEMM3: += Pe^T @ ee1^T
    #pragma unroll
    for (int kb = 0; kb < 3; kb++) {
        bf16x8 A[6];
        #pragma unroll
        for (int m = 0; m < 6; m++) A[m] = __builtin_bit_cast(bf16x8, Ape[(m*3+kb)*64 + l]);
        #pragma unroll
        for (int n = 0; n < 4; n++) {
            bf16x8 Bf = __builtin_bit_cast(bf16x8, *(const u32x4*)&sB[((kb*4+n)*64 + l)*4]);
            #pragma unroll
            for (int m = 0; m < 6; m++) acc[m][n] = MFMA16(A[m], Bf, acc[m][n]);
        }
    }

    // rebuild edge_enc B-frags
    u32x4 ee[3][4];
    #pragma unroll
    for (int kb = 0; kb < 3; kb++)
      #pragma unroll
      for (int n = 0; n < 4; n++)
        #pragma unroll
        for (int p = 0; p < 4; p++) {
            int h = 32*kb + 8*gq + 2*p;
            int j = 16*n + cL;
            float a0 = fmaxf(wr[h]   + wst[h*NN + j],     0.f);
            float a1 = fmaxf(wr[h+1] + wst[(h+1)*NN + j], 0.f);
            ee[kb][n][p] = pk2(a0, a1);
        }

    // GEMM4: += Pc^T @ EE^T
    #pragma unroll
    for (int kb = 0; kb < 3; kb++) {
        bf16x8 A[6];
        #pragma unroll
        for (int m = 0; m < 6; m++) A[m] = __builtin_bit_cast(bf16x8, Apc[(m*3+kb)*64 + l]);
        #pragma unroll
        for (int n = 0; n < 4; n++) {
            bf16x8 Bf = __builtin_bit_cast(bf16x8, ee[kb][n]);
            #pragma unroll
            for (int m = 0; m < 6; m++) acc[m][n] = MFMA16(A[m], Bf, acc[m][n]);
        }
    }

    // relu + repack tp -> LDS B-frags
    #pragma unroll
    for (int m = 0; m < 6; m++)
      #pragma unroll
      for (int n = 0; n < 4; n++) {
        float v0 = fmaxf(acc[m][n][0],0.f), v1 = fmaxf(acc[m][n][1],0.f);
        float v2 = fmaxf(acc[m][n][2],0.f), v3 = fmaxf(acc[m][n][3],0.f);
        int gd = 2*(m&1) + (gq>>1);
        int dw = (((m>>1)*4 + n)*64 + 16*gd + cL)*4 + 2*(gq&1);
        sB[dw]   = pk2(v0,v1);
        sB[dw+1] = pk2(v2,v3);
      }

    // GEMM5: out^T = P2^T @ tp^T  (M=16 padded, rows 0,1 valid)
    f32x4 c5[4];
    #pragma unroll
    for (int n = 0; n < 4; n++) {
        c5[n][0] = (gq == 0) ? pred_b2[0] : 0.f;
        c5[n][1] = (gq == 0) ? pred_b2[1] : 0.f;
        c5[n][2] = 0.f; c5[n][3] = 0.f;
    }
    #pragma unroll
    for (int kb = 0; kb < 3; kb++) {
        bf16x8 A2 = __builtin_bit_cast(bf16x8, Ap2[kb*64 + l]);
        #pragma unroll
        for (int n = 0; n < 4; n++) {
            bf16x8 Bf = __builtin_bit_cast(bf16x8, *(const u32x4*)&sB[((kb*4+n)*64 + l)*4]);
            c5[n] = MFMA16(A2, Bf, c5[n]);
        }
    }
    if (gq == 0) {
        float2* o2 = (float2*)out;
        #pragma unroll
        for (int n = 0; n < 4; n++) {
            size_t j = 16*n + cL;
            o2[(((size_t)(b*NN + i))*NN + j)*RR + r] = make_float2(c5[n][0], c5[n][1]);
        }
    }
}

// ---------------------------------------------------------------------------
extern "C" void kernel_launch(void* const* d_in, const int* in_sizes, int n_in,
                              void* d_out, int out_size, void* d_ws, size_t ws_size,
                              hipStream_t stream)
{
    const float* node_rep = (const float*)d_in[0];
    const float* ne_W    = (const float*)d_in[1];
    const float* ne_b    = (const float*)d_in[2];
    const float* ee_W    = (const float*)d_in[3];
    const float* ee_b    = (const float*)d_in[4];
    const float* np_W1   = (const float*)d_in[5];
    const float* np_b1   = (const float*)d_in[6];
    const float* np_W2   = (const float*)d_in[7];
    const float* np_b2   = (const float*)d_in[8];
    const float* ep0_W1  = (const float*)d_in[9];
    const float* ep0_b1  = (const float*)d_in[10];
    const float* ep0_W2  = (const float*)d_in[11];
    const float* ep0_b2  = (const float*)d_in[12];
    const float* ep1_W1  = (const float*)d_in[13];
    const float* ep1_b1  = (const float*)d_in[14];
    const float* ep1_W2  = (const float*)d_in[15];
    const float* ep1_b2  = (const float*)d_in[16];
    const float* pred_W1 = (const float*)d_in[17];
    const float* pred_b1 = (const float*)d_in[18];
    const float* pred_W2 = (const float*)d_in[19];
    const float* pred_b2 = (const float*)d_in[20];
    float* wsf = (float*)d_ws;
    float* out = (float*)d_out;

    float* wr_r = wsf + OFF_WR;
    float* ws_t = wsf + OFF_WS_T;
    float* ner0 = wsf + OFF_NER0;
    float* nes0 = wsf + OFF_NES0;
    float* ner1 = wsf + OFF_NER1;
    float* nes1 = wsf + OFF_NES1;
    float* enc  = wsf + OFF_ENC;
    float* agg  = wsf + OFF_AGG;
    unsigned int* pk_w = (unsigned int*)(wsf + OFF_PKW);
    unsigned int* ee0f = (unsigned int*)(wsf + OFF_EE0F);

    k1_node<<<NGROUP + 111, 64, 0, stream>>>(node_rep, ne_W, ne_b, ee_W, ee_b,
                                             ep0_W1, ep0_b1, ep0_W2,
                                             ep1_W1, ep1_W2, pred_W1, pred_W2,
                                             wr_r, ws_t, ner0, nes0, enc, pk_w);

    k2_edge0<<<NGROUP, 64, 0, stream>>>(wr_r, ws_t, ner0, nes0, pk_w, ep0_b2,
                                        ee0f, agg);

    k3_node<<<NGROUP, 64, 0, stream>>>(enc, agg, np_W1, np_b1, np_W2, np_b2,
                                       ep1_W1, ep1_b1, ner1, nes1);

    k4_edge1<<<NGROUP, 64, 0, stream>>>(wr_r, ws_t, ner1, nes1, pk_w, ee0f,
                                        ep1_b2, pred_b1, pred_b2, out);
}

// Round 6
// 132.088 us; speedup vs baseline: 5.6247x; 1.4156x over previous
//
#include <hip/hip_runtime.h>
#include <hip/hip_bf16.h>

#define BB 4
#define NN 64
#define RR 8
#define DD 32
#define HH 96
#define NGROUP (BB*NN*RR)   // 2048

// workspace float offsets — all node-side tensors transposed [b*8+r][feat][node]
#define OFF_WR_T  0
#define OFF_WS_T  196608
#define OFF_NER0  393216
#define OFF_NES0  589824
#define OFF_NER1  786432
#define OFF_NES1  983040
#define OFF_ENCT  1179648
#define OFF_AGGT  1376256
#define OFF_PKE   1572864      // edge-side packed weights (hi only), 28416 u32
#define OFF_PKN   1601280      // node-side packed weights (hi+lo), 73728 u32
#define OFF_EE0F  1675008      // ee0 in B-frag bf16 form, 2048*3072 u32

// pk_e u32 offsets (frag = 256 u32; 96x96 mat = 18 frags = 4608)
#define PE_EE0  0
#define PE_W20  4608
#define PE_EE1  9216
#define PE_W21  13824
#define PE_PE   18432
#define PE_PC   23040
#define PE_P2   27648
// pk_n u32 offsets (K=32 mats: 6 frags = 1536/part; K=96 mats: 4608/part; hi then lo)
#define PN_NEW  0
#define PN_WR   3072
#define PN_WS   6144
#define PN_ER0  9216
#define PN_ES0  18432
#define PN_WN12 27648
#define PN_WN3  36864
#define PN_NPW2 46080
#define PN_ER1  55296
#define PN_ES1  64512

typedef __attribute__((ext_vector_type(4))) float f32x4;
typedef __attribute__((ext_vector_type(8))) short bf16x8;
typedef __attribute__((ext_vector_type(4))) unsigned int u32x4;

__device__ __forceinline__ unsigned int pk2(float lo, float hi){
    unsigned short a = __builtin_bit_cast(unsigned short, __float2bfloat16(lo));
    unsigned short b = __builtin_bit_cast(unsigned short, __float2bfloat16(hi));
    return (unsigned)a | ((unsigned)b << 16);
}
// split v into bf16 hi + bf16 lo residual (x ~ hi + lo to ~2^-17 rel)
__device__ __forceinline__ void split2(float v0, float v1, unsigned &h, unsigned &lo){
    float h0 = __bfloat162float(__float2bfloat16(v0));
    float h1 = __bfloat162float(__float2bfloat16(v1));
    h  = pk2(v0, v1);
    lo = pk2(v0 - h0, v1 - h1);
}

#define MFMA16(A,B,C) __builtin_amdgcn_mfma_f32_16x16x32_bf16((A),(B),(C),0,0,0)

// ---------------- shared helpers (M=96 x rows=64 tile; acc[m][nt][q]) -------
__device__ __forceinline__ void cinit(f32x4 (&acc)[6][4], const float* __restrict__ bv, int gq){
    #pragma unroll
    for (int m=0;m<6;m++)
      #pragma unroll
      for (int q=0;q<4;q++){
        float x = bv[16*m+4*gq+q];
        #pragma unroll
        for (int nt=0;nt<4;nt++) acc[m][nt][q] = x;
      }
}
__device__ __forceinline__ void cinit0(f32x4 (&acc)[6][4]){
    #pragma unroll
    for (int m=0;m<6;m++)
      #pragma unroll
      for (int nt=0;nt<4;nt++)
        #pragma unroll
        for (int q=0;q<4;q++) acc[m][nt][q] = 0.f;
}
__device__ __forceinline__ void relu_acc(f32x4 (&acc)[6][4]){
    #pragma unroll
    for (int m=0;m<6;m++)
      #pragma unroll
      for (int nt=0;nt<4;nt++)
        #pragma unroll
        for (int q=0;q<4;q++) acc[m][nt][q] = fmaxf(acc[m][nt][q], 0.f);
}
// split GEMM step for one kb: acc += Ah@Bh + Ah@Bl + Al@Bh
__device__ __forceinline__ void gemm_kb(f32x4 (&acc)[6][4],
    const unsigned* __restrict__ ph, const unsigned* __restrict__ pl,
    int nkb, int kb, int l, const u32x4 (&Bh)[4], const u32x4 (&Bl)[4])
{
    #pragma unroll
    for (int m=0;m<6;m++){
        bf16x8 ah = __builtin_bit_cast(bf16x8, *(const u32x4*)&ph[(m*nkb+kb)*256 + l*4]);
        bf16x8 al = __builtin_bit_cast(bf16x8, *(const u32x4*)&pl[(m*nkb+kb)*256 + l*4]);
        #pragma unroll
        for (int nt=0;nt<4;nt++){
            bf16x8 bh = __builtin_bit_cast(bf16x8, Bh[nt]);
            bf16x8 bl = __builtin_bit_cast(bf16x8, Bl[nt]);
            acc[m][nt] = MFMA16(ah, bh, acc[m][nt]);
            acc[m][nt] = MFMA16(ah, bl, acc[m][nt]);
            acc[m][nt] = MFMA16(al, bh, acc[m][nt]);
        }
    }
}
__device__ __forceinline__ void gemm_lds(f32x4 (&acc)[6][4],
    const unsigned* __restrict__ ph, const unsigned* __restrict__ pl,
    int kb, int l, const unsigned* sBh, const unsigned* sBl)
{
    u32x4 Bh[4], Bl[4];
    #pragma unroll
    for (int nt=0;nt<4;nt++){
        Bh[nt] = *(const u32x4*)&sBh[((kb*4+nt)*64 + l)*4];
        Bl[nt] = *(const u32x4*)&sBl[((kb*4+nt)*64 + l)*4];
    }
    gemm_kb(acc, ph, pl, 3, kb, l, Bh, Bl);
}
// repack acc (feat c x row) -> B-frag layout in LDS, with hi/lo split
__device__ __forceinline__ void repack(const f32x4 (&acc)[6][4],
    unsigned* sBh, unsigned* sBl, int gq, int cL)
{
    #pragma unroll
    for (int m=0;m<6;m++)
      #pragma unroll
      for (int nt=0;nt<4;nt++){
        int gd = 2*(m&1) + (gq>>1);
        int dw = (((m>>1)*4 + nt)*64 + 16*gd + cL)*4 + 2*(gq&1);
        split2(acc[m][nt][0], acc[m][nt][1], sBh[dw],   sBl[dw]);
        split2(acc[m][nt][2], acc[m][nt][3], sBh[dw+1], sBl[dw+1]);
      }
}
// store acc transposed: dst[feat][row], coalesced in 16-lane groups
__device__ __forceinline__ void storeT(const f32x4 (&acc)[6][4], float* __restrict__ dst,
                                       int gq, int cL){
    #pragma unroll
    for (int m=0;m<6;m++)
      #pragma unroll
      for (int nt=0;nt<4;nt++)
        #pragma unroll
        for (int q=0;q<4;q++)
            dst[(16*m+4*gq+q)*NN + 16*nt + cL] = acc[m][nt][q];
}
// build split B-frags from transposed fp32 src [feat][64]
__device__ __forceinline__ void buildB(const float* __restrict__ src_t, int kb, int gq, int cL,
                                       u32x4 (&Bh)[4], u32x4 (&Bl)[4]){
    #pragma unroll
    for (int nt=0;nt<4;nt++)
      #pragma unroll
      for (int p=0;p<4;p++){
        int k = 32*kb + 8*gq + 2*p;
        int col = 16*nt + cL;
        unsigned h, lo;
        split2(src_t[k*NN+col], src_t[(k+1)*NN+col], h, lo);
        Bh[nt][p] = h; Bl[nt][p] = lo;
      }
}

// ---------------------------------------------------------------------------
// K0: pack all weights into MFMA A-frags. grid 255 x 64.
// ---------------------------------------------------------------------------
__global__ __launch_bounds__(64)
void k0_pack(const float* __restrict__ ne_W, const float* __restrict__ ee_W,
             const float* __restrict__ ep0_W1, const float* __restrict__ ep0_W2,
             const float* __restrict__ ep1_W1, const float* __restrict__ ep1_W2,
             const float* __restrict__ np_W1, const float* __restrict__ np_W2,
             const float* __restrict__ pred_W1, const float* __restrict__ pred_W2,
             unsigned* __restrict__ pk_e, unsigned* __restrict__ pk_n)
{
    int t = blockIdx.x, l = threadIdx.x;
    int cL = l & 15, gq = l >> 4;
    if (t < 108) {                         // edge-side, hi only
        int mat = t/18, tt = t%18, mt = tt/3, kb = tt%3;
        const float* mats[6] = { ep0_W1 + 2*HH*HH, ep0_W2, ep1_W1 + 2*HH*HH,
                                 ep1_W2, pred_W1, pred_W1 + HH*HH };
        const float* src = mats[mat];
        u32x4 d;
        #pragma unroll
        for (int p=0;p<4;p++){
            int k = 32*kb + 8*gq + 2*p;
            d[p] = pk2(src[k*HH + 16*mt + cL], src[(k+1)*HH + 16*mt + cL]);
        }
        *(u32x4*)&pk_e[mat*4608 + (mt*3+kb)*256 + l*4] = d;
    } else if (t < 111) {                  // pred_W2 zero-padded to 16 cols
        int kb = t - 108;
        u32x4 d;
        #pragma unroll
        for (int p=0;p<4;p++){
            int k = 32*kb + 8*gq + 2*p;
            float lo = (cL < 2) ? pred_W2[k*2 + cL]     : 0.f;
            float hi = (cL < 2) ? pred_W2[(k+1)*2 + cL] : 0.f;
            d[p] = pk2(lo, hi);
        }
        *(u32x4*)&pk_e[PE_P2 + kb*256 + l*4] = d;
    } else {
        int u = t - 111;
        if (u < 18) {                      // K=32 node mats: neW, Wr, Ws (hi+lo)
            int mat = u/6, mt = u%6;
            const float* srcs[3] = { ne_W, ee_W, ee_W + DD*HH };
            const float* src = srcs[mat];
            u32x4 dh, dl;
            #pragma unroll
            for (int p=0;p<4;p++){
                int k = 8*gq + 2*p;
                unsigned th, tl;
                split2(src[k*HH + 16*mt + cL], src[(k+1)*HH + 16*mt + cL], th, tl);
                dh[p] = th; dl[p] = tl;
            }
            int base = mat*3072 + mt*256 + l*4;
            *(u32x4*)&pk_n[base]        = dh;
            *(u32x4*)&pk_n[base + 1536] = dl;
        } else {                           // K=96 node mats (hi+lo)
            int u2 = u-18, mat = u2/18, tt = u2%18, mt = tt/3, kb = tt%3;
            u32x4 dh, dl;
            #pragma unroll
            for (int p=0;p<4;p++){
                int k = 32*kb + 8*gq + 2*p, col = 16*mt + cL;
                float v0, v1;
                if (mat == 2) {            // Wn12 = Wn1 + Wn2
                    v0 = np_W1[k*HH+col]     + np_W1[(HH+k)*HH+col];
                    v1 = np_W1[(k+1)*HH+col] + np_W1[(HH+k+1)*HH+col];
                } else {
                    const float* src = (mat==0) ? ep0_W1
                                     : (mat==1) ? ep0_W1 + HH*HH
                                     : (mat==3) ? np_W1 + 2*HH*HH
                                     : (mat==4) ? np_W2
                                     : (mat==5) ? ep1_W1
                                     :            ep1_W1 + HH*HH;
                    v0 = src[k*HH+col]; v1 = src[(k+1)*HH+col];
                }
                unsigned th, tl;
                split2(v0, v1, th, tl);
                dh[p] = th; dl[p] = tl;
            }
            int base = PN_ER0 + mat*9216 + (mt*3+kb)*256 + l*4;
            *(u32x4*)&pk_n[base]        = dh;
            *(u32x4*)&pk_n[base + 4608] = dl;
        }
    }
}

// ---------------------------------------------------------------------------
// K1: node encode + all step-0 projections via split-MFMA. grid 32 x 64.
// wave br=(b,r) owns rows n=0..63 (g = (b*64+n)*8+r).
// ---------------------------------------------------------------------------
__global__ __launch_bounds__(64)
void k1_node(const float* __restrict__ node_rep,
             const float* __restrict__ ne_b, const float* __restrict__ ee_b,
             const float* __restrict__ ep0_b1,
             const unsigned* __restrict__ pk_n,
             float* __restrict__ wr_t, float* __restrict__ ws_t,
             float* __restrict__ ner0_t, float* __restrict__ nes0_t,
             float* __restrict__ enc_t)
{
    int br = blockIdx.x, l = threadIdx.x;
    int b = br >> 3, r = br & 7;
    int cL = l & 15, gq = l >> 4;
    __shared__ __align__(16) unsigned sBh[3072], sBl[3072];
    size_t brb = (size_t)br * HH * NN;

    // node_rep B-frags (K=32, single kb)
    u32x4 nBh[4], nBl[4];
    #pragma unroll
    for (int nt=0;nt<4;nt++)
      #pragma unroll
      for (int p=0;p<4;p++){
        int k = 8*gq + 2*p;
        int row = 16*nt + cL;
        const float* s = node_rep + ((size_t)((b*NN+row)*RR + r))*DD + k;
        unsigned h, lo;
        split2(s[0], s[1], h, lo);
        nBh[nt][p] = h; nBl[nt][p] = lo;
      }

    f32x4 acc[6][4];

    // enc = relu(node @ neW + ne_b)
    cinit(acc, ne_b, gq);
    gemm_kb(acc, pk_n+PN_NEW, pk_n+PN_NEW+1536, 1, 0, l, nBh, nBl);
    relu_acc(acc);
    storeT(acc, enc_t + brb, gq, cL);
    repack(acc, sBh, sBl, gq, cL);

    // ner0 = enc @ Er0 + ep0_b1
    cinit(acc, ep0_b1, gq);
    #pragma unroll
    for (int kb=0;kb<3;kb++) gemm_lds(acc, pk_n+PN_ER0, pk_n+PN_ER0+4608, kb, l, sBh, sBl);
    storeT(acc, ner0_t + brb, gq, cL);

    // nes0 = enc @ Es0
    cinit0(acc);
    #pragma unroll
    for (int kb=0;kb<3;kb++) gemm_lds(acc, pk_n+PN_ES0, pk_n+PN_ES0+4608, kb, l, sBh, sBl);
    storeT(acc, nes0_t + brb, gq, cL);

    // wr' = node @ Wr + ee_b
    cinit(acc, ee_b, gq);
    gemm_kb(acc, pk_n+PN_WR, pk_n+PN_WR+1536, 1, 0, l, nBh, nBl);
    storeT(acc, wr_t + brb, gq, cL);

    // ws = node @ Ws
    cinit0(acc);
    gemm_kb(acc, pk_n+PN_WS, pk_n+PN_WS+1536, 1, 0, l, nBh, nBl);
    storeT(acc, ws_t + brb, gq, cL);
}

// ---------------------------------------------------------------------------
// K2: edge prop step 0 via MFMA (plain bf16). 1 wave per g.
// ---------------------------------------------------------------------------
__global__ __launch_bounds__(64)
void k2_edge0(const float* __restrict__ wr_t, const float* __restrict__ ws_t,
              const float* __restrict__ ner0_t, const float* __restrict__ nes0_t,
              const unsigned* __restrict__ pk_e,
              const float* __restrict__ ep0_b2,
              unsigned* __restrict__ ee0f, float* __restrict__ agg_t)
{
    int g = blockIdx.x, l = threadIdx.x;
    int b = g >> 9, r = g & 7, i = (g >> 3) & 63;
    int cL = l & 15, gq = l >> 4;
    size_t brb = (size_t)(b*RR + r)*HH*NN;
    const float* wrt = wr_t   + brb;
    const float* nrt = ner0_t + brb;
    const float* wst = ws_t   + brb;
    const float* nst = nes0_t + brb;
    const unsigned* Ae = pk_e + PE_EE0;
    const unsigned* Aw = pk_e + PE_W20;
    __shared__ __align__(16) unsigned sB[3072];

    // edge_enc B-frags
    u32x4 ee[3][4];
    #pragma unroll
    for (int kb=0;kb<3;kb++)
      #pragma unroll
      for (int n=0;n<4;n++)
        #pragma unroll
        for (int p=0;p<4;p++){
            int h = 32*kb + 8*gq + 2*p;
            int j = 16*n + cL;
            float a0 = fmaxf(wrt[h*NN + i]     + wst[h*NN + j],     0.f);
            float a1 = fmaxf(wrt[(h+1)*NN + i] + wst[(h+1)*NN + j], 0.f);
            ee[kb][n][p] = pk2(a0, a1);
        }

    f32x4 acc[6][4];
    #pragma unroll
    for (int m=0;m<6;m++)
      #pragma unroll
      for (int q=0;q<4;q++){
        int c = 16*m + 4*gq + q;
        float nr = nrt[c*NN + i];
        #pragma unroll
        for (int n=0;n<4;n++) acc[m][n][q] = nr + nst[c*NN + 16*n + cL];
      }

    // GEMM1: t0 = Ee0^T @ edge_enc^T
    #pragma unroll
    for (int kb=0;kb<3;kb++){
        bf16x8 A[6];
        #pragma unroll
        for (int m=0;m<6;m++) A[m] = __builtin_bit_cast(bf16x8, *(const u32x4*)&Ae[((m*3+kb)*64 + l)*4]);
        #pragma unroll
        for (int n=0;n<4;n++){
            bf16x8 Bf = __builtin_bit_cast(bf16x8, ee[kb][n]);
            #pragma unroll
            for (int m=0;m<6;m++) acc[m][n] = MFMA16(A[m], Bf, acc[m][n]);
        }
    }

    // relu + repack -> LDS B-frags (plain bf16)
    #pragma unroll
    for (int m=0;m<6;m++)
      #pragma unroll
      for (int n=0;n<4;n++){
        float v0 = fmaxf(acc[m][n][0],0.f), v1 = fmaxf(acc[m][n][1],0.f);
        float v2 = fmaxf(acc[m][n][2],0.f), v3 = fmaxf(acc[m][n][3],0.f);
        int gd = 2*(m&1) + (gq>>1);
        int dw = (((m>>1)*4 + n)*64 + 16*gd + cL)*4 + 2*(gq&1);
        sB[dw]   = pk2(v0,v1);
        sB[dw+1] = pk2(v2,v3);
      }

    #pragma unroll
    for (int m=0;m<6;m++)
      #pragma unroll
      for (int q=0;q<4;q++){
        float bv = ep0_b2[16*m + 4*gq + q];
        #pragma unroll
        for (int n=0;n<4;n++) acc[m][n][q] = bv;
      }

    // GEMM2: ee0 = W20^T @ t0^T
    #pragma unroll
    for (int kb=0;kb<3;kb++){
        bf16x8 A[6];
        #pragma unroll
        for (int m=0;m<6;m++) A[m] = __builtin_bit_cast(bf16x8, *(const u32x4*)&Aw[((m*3+kb)*64 + l)*4]);
        #pragma unroll
        for (int n=0;n<4;n++){
            bf16x8 Bf = __builtin_bit_cast(bf16x8, *(const u32x4*)&sB[((kb*4+n)*64 + l)*4]);
            #pragma unroll
            for (int m=0;m<6;m++) acc[m][n] = MFMA16(A[m], Bf, acc[m][n]);
        }
    }

    #pragma unroll
    for (int m=0;m<6;m++)
      #pragma unroll
      for (int n=0;n<4;n++)
        #pragma unroll
        for (int q=0;q<4;q++) acc[m][n][q] = fmaxf(acc[m][n][q], 0.f);

    // store ee0 frags (B-layout bf16) + agg reduce (transposed write)
    unsigned* eo = ee0f + (size_t)g*3072;
    #pragma unroll
    for (int m=0;m<6;m++)
      #pragma unroll
      for (int n=0;n<4;n++){
        int gd = 2*(m&1) + (gq>>1);
        int dw = (((m>>1)*4 + n)*64 + 16*gd + cL)*4 + 2*(gq&1);
        eo[dw]   = pk2(acc[m][n][0], acc[m][n][1]);
        eo[dw+1] = pk2(acc[m][n][2], acc[m][n][3]);
      }
    #pragma unroll
    for (int m=0;m<6;m++)
      #pragma unroll
      for (int q=0;q<4;q++){
        float s = acc[m][0][q] + acc[m][1][q] + acc[m][2][q] + acc[m][3][q];
        s += __shfl_xor(s, 1);
        s += __shfl_xor(s, 2);
        s += __shfl_xor(s, 4);
        s += __shfl_xor(s, 8);
        if (cL == 0) agg_t[brb + (16*m + 4*gq + q)*NN + i] = s;
      }
}

// ---------------------------------------------------------------------------
// K3: node update + step-1 projections via split-MFMA. grid 32 x 64.
// ---------------------------------------------------------------------------
__global__ __launch_bounds__(64)
void k3_node(const float* __restrict__ enc_t_g, const float* __restrict__ agg_t_g,
             const float* __restrict__ np_b1, const float* __restrict__ np_b2,
             const float* __restrict__ ep1_b1,
             const unsigned* __restrict__ pk_n,
             float* __restrict__ ner1_t, float* __restrict__ nes1_t)
{
    int br = blockIdx.x, l = threadIdx.x;
    int cL = l & 15, gq = l >> 4;
    __shared__ __align__(16) unsigned sBh[3072], sBl[3072];
    size_t brb = (size_t)br * HH * NN;
    const float* enc_t = enc_t_g + brb;
    const float* agg_t = agg_t_g + brb;

    f32x4 acc[6][4];

    // t = relu(enc @ Wn12 + agg @ Wn3 + np_b1)
    cinit(acc, np_b1, gq);
    #pragma unroll
    for (int kb=0;kb<3;kb++){
        u32x4 Bh[4], Bl[4];
        buildB(enc_t, kb, gq, cL, Bh, Bl);
        gemm_kb(acc, pk_n+PN_WN12, pk_n+PN_WN12+4608, 3, kb, l, Bh, Bl);
    }
    #pragma unroll
    for (int kb=0;kb<3;kb++){
        u32x4 Bh[4], Bl[4];
        buildB(agg_t, kb, gq, cL, Bh, Bl);
        gemm_kb(acc, pk_n+PN_WN3, pk_n+PN_WN3+4608, 3, kb, l, Bh, Bl);
    }
    relu_acc(acc);
    repack(acc, sBh, sBl, gq, cL);

    // ne1 = relu(t @ npW2 + np_b2)
    cinit(acc, np_b2, gq);
    #pragma unroll
    for (int kb=0;kb<3;kb++) gemm_lds(acc, pk_n+PN_NPW2, pk_n+PN_NPW2+4608, kb, l, sBh, sBl);
    relu_acc(acc);
    repack(acc, sBh, sBl, gq, cL);

    // ner1 = ne1 @ Er1 + ep1_b1
    cinit(acc, ep1_b1, gq);
    #pragma unroll
    for (int kb=0;kb<3;kb++) gemm_lds(acc, pk_n+PN_ER1, pk_n+PN_ER1+4608, kb, l, sBh, sBl);
    storeT(acc, ner1_t + brb, gq, cL);

    // nes1 = ne1 @ Es1
    cinit0(acc);
    #pragma unroll
    for (int kb=0;kb<3;kb++) gemm_lds(acc, pk_n+PN_ES1, pk_n+PN_ES1+4608, kb, l, sBh, sBl);
    storeT(acc, nes1_t + brb, gq, cL);
}

// ---------------------------------------------------------------------------
// K4: edge prop step 1 + prediction head via MFMA. 1 wave per g.
// ---------------------------------------------------------------------------
__global__ __launch_bounds__(64)
void k4_edge1(const float* __restrict__ wr_t, const float* __restrict__ ws_t,
              const float* __restrict__ ner1_t, const float* __restrict__ nes1_t,
              const unsigned* __restrict__ pk_e,
              const unsigned* __restrict__ ee0f,
              const float* __restrict__ ep1_b2,
              const float* __restrict__ pred_b1, const float* __restrict__ pred_b2,
              float* __restrict__ out)
{
    int g = blockIdx.x, l = threadIdx.x;
    int b = g >> 9, i = (g >> 3) & 63, r = g & 7;
    int cL = l & 15, gq = l >> 4;
    size_t brb = (size_t)(b*RR + r)*HH*NN;
    const float* wrt = wr_t   + brb;
    const float* wst = ws_t   + brb;
    const float* nrt = ner1_t + brb;
    const float* nst = nes1_t + brb;
    const unsigned* Ae1 = pk_e + PE_EE1;
    const unsigned* Aw1 = pk_e + PE_W21;
    const unsigned* Ape = pk_e + PE_PE;
    const unsigned* Apc = pk_e + PE_PC;
    const unsigned* Ap2 = pk_e + PE_P2;
    __shared__ __align__(16) unsigned sB[3072];

    const u32x4* e0p = (const u32x4*)ee0f + (size_t)g*768;
    u32x4 bf0[3][4];
    #pragma unroll
    for (int kb=0;kb<3;kb++)
      #pragma unroll
      for (int n=0;n<4;n++) bf0[kb][n] = e0p[(kb*4+n)*64 + l];

    f32x4 acc[6][4];
    #pragma unroll
    for (int m=0;m<6;m++)
      #pragma unroll
      for (int q=0;q<4;q++){
        int c = 16*m + 4*gq + q;
        float nr = nrt[c*NN + i];
        #pragma unroll
        for (int n=0;n<4;n++) acc[m][n][q] = nr + nst[c*NN + 16*n + cL];
      }

    // GEMM1: t1 = Ee1^T @ ee0^T
    #pragma unroll
    for (int kb=0;kb<3;kb++){
        bf16x8 A[6];
        #pragma unroll
        for (int m=0;m<6;m++) A[m] = __builtin_bit_cast(bf16x8, *(const u32x4*)&Ae1[((m*3+kb)*64 + l)*4]);
        #pragma unroll
        for (int n=0;n<4;n++){
            bf16x8 Bf = __builtin_bit_cast(bf16x8, bf0[kb][n]);
            #pragma unroll
            for (int m=0;m<6;m++) acc[m][n] = MFMA16(A[m], Bf, acc[m][n]);
        }
    }

    // relu + repack t1 -> LDS
    #pragma unroll
    for (int m=0;m<6;m++)
      #pragma unroll
      for (int n=0;n<4;n++){
        float v0 = fmaxf(acc[m][n][0],0.f), v1 = fmaxf(acc[m][n][1],0.f);
        float v2 = fmaxf(acc[m][n][2],0.f), v3 = fmaxf(acc[m][n][3],0.f);
        int gd = 2*(m&1) + (gq>>1);
        int dw = (((m>>1)*4 + n)*64 + 16*gd + cL)*4 + 2*(gq&1);
        sB[dw]   = pk2(v0,v1);
        sB[dw+1] = pk2(v2,v3);
      }

    #pragma unroll
    for (int m=0;m<6;m++)
      #pragma unroll
      for (int q=0;q<4;q++){
        float bv = ep1_b2[16*m + 4*gq + q];
        #pragma unroll
        for (int n=0;n<4;n++) acc[m][n][q] = bv;
      }

    // GEMM2: ee1 = W21^T @ t1^T
    #pragma unroll
    for (int kb=0;kb<3;kb++){
        bf16x8 A[6];
        #pragma unroll
        for (int m=0;m<6;m++) A[m] = __builtin_bit_cast(bf16x8, *(const u32x4*)&Aw1[((m*3+kb)*64 + l)*4]);
        #pragma unroll
        for (int n=0;n<4;n++){
            bf16x8 Bf = __builtin_bit_cast(bf16x8, *(const u32x4*)&sB[((kb*4+n)*64 + l)*4]);
            #pragma unroll
            for (int m=0;m<6;m++) acc[m][n] = MFMA16(A[m], Bf, acc[m][n]);
        }
    }

    // relu + repack ee1 -> LDS
    #pragma unroll
    for (int m=0;m<6;m++)
      #pragma unroll
      for (int n=0;n<4;n++){
        float v0 = fmaxf(acc[m][n][0],0.f), v1 = fmaxf(acc[m][n][1],0.f);
        float v2 = fmaxf(acc[m][n][2],0.f), v3 = fmaxf(acc[m][n][3],0.f);
        int gd = 2*(m&1) + (gq>>1);
        int dw = (((m>>1)*4 + n)*64 + 16*gd + cL)*4 + 2*(gq&1);
        sB[dw]   = pk2(v0,v1);
        sB[dw+1] = pk2(v2,v3);
      }

    #pragma unroll
    for (int m=0;m<6;m++)
      #pragma unroll
      for (int q=0;q<4;q++){
        float bv = pred_b1[16*m + 4*gq + q];
        #pragma unroll
        for (int n=0;n<4;n++) acc[m][n][q] = bv;
      }

    // GEMM3: += Pe^T @ ee1^T
    #pragma unroll
    for (int kb=0;kb<3;kb++){
        bf16x8 A[6];
        #pragma unroll
        for (int m=0;m<6;m++) A[m] = __builtin_bit_cast(bf16x8, *(const u32x4*)&Ape[((m*3+kb)*64 + l)*4]);
        #pragma unroll
        for (int n=0;n<4;n++){
            bf16x8 Bf = __builtin_bit_cast(bf16x8, *(const u32x4*)&sB[((kb*4+n)*64 + l)*4]);
            #pragma unroll
            for (int m=0;m<6;m++) acc[m][n] = MFMA16(A[m], Bf, acc[m][n]);
        }
    }

    // rebuild edge_enc B-frags
    u32x4 ee[3][4];
    #pragma unroll
    for (int kb=0;kb<3;kb++)
      #pragma unroll
      for (int n=0;n<4;n++)
        #pragma unroll
        for (int p=0;p<4;p++){
            int h = 32*kb + 8*gq + 2*p;
            int j = 16*n + cL;
            float a0 = fmaxf(wrt[h*NN + i]     + wst[h*NN + j],     0.f);
            float a1 = fmaxf(wrt[(h+1)*NN + i] + wst[(h+1)*NN + j], 0.f);
            ee[kb][n][p] = pk2(a0, a1);
        }

    // GEMM4: += Pc^T @ edge_enc^T
    #pragma unroll
    for (int kb=0;kb<3;kb++){
        bf16x8 A[6];
        #pragma unroll
        for (int m=0;m<6;m++) A[m] = __builtin_bit_cast(bf16x8, *(const u32x4*)&Apc[((m*3+kb)*64 + l)*4]);
        #pragma unroll
        for (int n=0;n<4;n++){
            bf16x8 Bf = __builtin_bit_cast(bf16x8, ee[kb][n]);
            #pragma unroll
            for (int m=0;m<6;m++) acc[m][n] = MFMA16(A[m], Bf, acc[m][n]);
        }
    }

    // relu + repack tp -> LDS
    #pragma unroll
    for (int m=0;m<6;m++)
      #pragma unroll
      for (int n=0;n<4;n++){
        float v0 = fmaxf(acc[m][n][0],0.f), v1 = fmaxf(acc[m][n][1],0.f);
        float v2 = fmaxf(acc[m][n][2],0.f), v3 = fmaxf(acc[m][n][3],0.f);
        int gd = 2*(m&1) + (gq>>1);
        int dw = (((m>>1)*4 + n)*64 + 16*gd + cL)*4 + 2*(gq&1);
        sB[dw]   = pk2(v0,v1);
        sB[dw+1] = pk2(v2,v3);
      }

    // GEMM5: out = P2^T @ tp^T (rows 0,1 valid)
    f32x4 c5[4];
    #pragma unroll
    for (int n=0;n<4;n++){
        c5[n][0] = (gq == 0) ? pred_b2[0] : 0.f;
        c5[n][1] = (gq == 0) ? pred_b2[1] : 0.f;
        c5[n][2] = 0.f; c5[n][3] = 0.f;
    }
    #pragma unroll
    for (int kb=0;kb<3;kb++){
        bf16x8 A2 = __builtin_bit_cast(bf16x8, *(const u32x4*)&Ap2[(kb*64 + l)*4]);
        #pragma unroll
        for (int n=0;n<4;n++){
            bf16x8 Bf = __builtin_bit_cast(bf16x8, *(const u32x4*)&sB[((kb*4+n)*64 + l)*4]);
            c5[n] = MFMA16(A2, Bf, c5[n]);
        }
    }
    if (gq == 0) {
        float2* o2 = (float2*)out;
        #pragma unroll
        for (int n=0;n<4;n++){
            size_t j = 16*n + cL;
            o2[(((size_t)(b*NN + i))*NN + j)*RR + r] = make_float2(c5[n][0], c5[n][1]);
        }
    }
}

// ---------------------------------------------------------------------------
extern "C" void kernel_launch(void* const* d_in, const int* in_sizes, int n_in,
                              void* d_out, int out_size, void* d_ws, size_t ws_size,
                              hipStream_t stream)
{
    const float* node_rep = (const float*)d_in[0];
    const float* ne_W    = (const float*)d_in[1];
    const float* ne_b    = (const float*)d_in[2];
    const float* ee_W    = (const float*)d_in[3];
    const float* ee_b    = (const float*)d_in[4];
    const float* np_W1   = (const float*)d_in[5];
    const float* np_b1   = (const float*)d_in[6];
    const float* np_W2   = (const float*)d_in[7];
    const float* np_b2   = (const float*)d_in[8];
    const float* ep0_W1  = (const float*)d_in[9];
    const float* ep0_b1  = (const float*)d_in[10];
    const float* ep0_W2  = (const float*)d_in[11];
    const float* ep0_b2  = (const float*)d_in[12];
    const float* ep1_W1  = (const float*)d_in[13];
    const float* ep1_b1  = (const float*)d_in[14];
    const float* ep1_W2  = (const float*)d_in[15];
    const float* ep1_b2  = (const float*)d_in[16];
    const float* pred_W1 = (const float*)d_in[17];
    const float* pred_b1 = (const float*)d_in[18];
    const float* pred_W2 = (const float*)d_in[19];
    const float* pred_b2 = (const float*)d_in[20];
    float* wsf = (float*)d_ws;
    float* out = (float*)d_out;

    float* wr_t   = wsf + OFF_WR_T;
    float* ws_t   = wsf + OFF_WS_T;
    float* ner0_t = wsf + OFF_NER0;
    float* nes0_t = wsf + OFF_NES0;
    float* ner1_t = wsf + OFF_NER1;
    float* nes1_t = wsf + OFF_NES1;
    float* enc_t  = wsf + OFF_ENCT;
    float* agg_t  = wsf + OFF_AGGT;
    unsigned* pk_e = (unsigned*)(wsf + OFF_PKE);
    unsigned* pk_n = (unsigned*)(wsf + OFF_PKN);
    unsigned* ee0f = (unsigned*)(wsf + OFF_EE0F);

    k0_pack<<<255, 64, 0, stream>>>(ne_W, ee_W, ep0_W1, ep0_W2, ep1_W1, ep1_W2,
                                    np_W1, np_W2, pred_W1, pred_W2, pk_e, pk_n);

    k1_node<<<32, 64, 0, stream>>>(node_rep, ne_b, ee_b, ep0_b1, pk_n,
                                   wr_t, ws_t, ner0_t, nes0_t, enc_t);

    k2_edge0<<<NGROUP, 64, 0, stream>>>(wr_t, ws_t, ner0_t, nes0_t, pk_e, ep0_b2,
                                        ee0f, agg_t);

    k3_node<<<32, 64, 0, stream>>>(enc_t, agg_t, np_b1, np_b2, ep1_b1, pk_n,
                                   ner1_t, nes1_t);

    k4_edge1<<<NGROUP, 64, 0, stream>>>(wr_t, ws_t, ner1_t, nes1_t, pk_e, ee0f,
                                        ep1_b2, pred_b1, pred_b2, out);
}

// Round 7
// 102.384 us; speedup vs baseline: 7.2565x; 1.2901x over previous
//
#include <hip/hip_runtime.h>
#include <hip/hip_bf16.h>

#define BB 4
#define NN 64
#define RR 8
#define DD 32
#define HH 96
#define NGROUP (BB*NN*RR)   // 2048
#define LSTR 17             // padded LDS stride (floats) for repack buffer

// workspace float offsets — all node-side tensors transposed [b*8+r][feat][node]
#define OFF_WR_T  0
#define OFF_WS_T  196608
#define OFF_NER0  393216
#define OFF_NES0  589824
#define OFF_NER1  786432
#define OFF_NES1  983040
#define OFF_ENCT  1179648
#define OFF_AGGT  1376256
#define OFF_PKE   1572864      // edge-side packed weights (hi only), 28416 u32
#define OFF_PKN   1601280      // node-side packed weights (hi+lo), 73728 u32
#define OFF_EE0F  1675008      // ee0 in B-frag bf16 form, 2048*3072 u32

// pk_e u32 offsets (frag = 256 u32; 96x96 mat = 18 frags = 4608)
#define PE_EE0  0
#define PE_W20  4608
#define PE_EE1  9216
#define PE_W21  13824
#define PE_PE   18432
#define PE_PC   23040
#define PE_P2   27648
// pk_n u32 offsets (K=32 mats: 6 frags = 1536/part; K=96 mats: 4608/part; hi then lo)
#define PN_NEW  0
#define PN_WR   3072
#define PN_WS   6144
#define PN_ER0  9216
#define PN_ES0  18432
#define PN_WN12 27648
#define PN_WN3  36864
#define PN_NPW2 46080
#define PN_ER1  55296
#define PN_ES1  64512

typedef __attribute__((ext_vector_type(4))) float f32x4;
typedef __attribute__((ext_vector_type(8))) short bf16x8;
typedef __attribute__((ext_vector_type(4))) unsigned int u32x4;

__device__ __forceinline__ unsigned int pk2(float lo, float hi){
    unsigned short a = __builtin_bit_cast(unsigned short, __float2bfloat16(lo));
    unsigned short b = __builtin_bit_cast(unsigned short, __float2bfloat16(hi));
    return (unsigned)a | ((unsigned)b << 16);
}
// split v into bf16 hi + bf16 lo residual (x ~ hi + lo to ~2^-17 rel)
__device__ __forceinline__ void split2(float v0, float v1, unsigned &h, unsigned &lo){
    float h0 = __bfloat162float(__float2bfloat16(v0));
    float h1 = __bfloat162float(__float2bfloat16(v1));
    h  = pk2(v0, v1);
    lo = pk2(v0 - h0, v1 - h1);
}

#define MFMA16(A,B,C) __builtin_amdgcn_mfma_f32_16x16x32_bf16((A),(B),(C),0,0,0)

// ================= 16-row node-kernel helpers (acc[6], one 16-col chunk) ====
__device__ __forceinline__ void cinit6(f32x4 (&acc)[6], const float* __restrict__ bv, int gq){
    #pragma unroll
    for (int m=0;m<6;m++)
      #pragma unroll
      for (int q=0;q<4;q++) acc[m][q] = bv[16*m+4*gq+q];
}
__device__ __forceinline__ void cinit6z(f32x4 (&acc)[6]){
    #pragma unroll
    for (int m=0;m<6;m++)
      #pragma unroll
      for (int q=0;q<4;q++) acc[m][q] = 0.f;
}
__device__ __forceinline__ void relu6(f32x4 (&acc)[6]){
    #pragma unroll
    for (int m=0;m<6;m++)
      #pragma unroll
      for (int q=0;q<4;q++) acc[m][q] = fmaxf(acc[m][q], 0.f);
}
// one kb of split GEMM: acc += Ah@Bh + Ah@Bl + Al@Bh (6 m-tiles)
__device__ __forceinline__ void gemm1(f32x4 (&acc)[6],
    const unsigned* __restrict__ ph, const unsigned* __restrict__ pl,
    int nkb, int kb, int l, const u32x4 &Bh, const u32x4 &Bl)
{
    bf16x8 bh = __builtin_bit_cast(bf16x8, Bh);
    bf16x8 bl = __builtin_bit_cast(bf16x8, Bl);
    #pragma unroll
    for (int m=0;m<6;m++){
        bf16x8 ah = __builtin_bit_cast(bf16x8, *(const u32x4*)&ph[(m*nkb+kb)*256 + l*4]);
        bf16x8 al = __builtin_bit_cast(bf16x8, *(const u32x4*)&pl[(m*nkb+kb)*256 + l*4]);
        acc[m] = MFMA16(ah, bh, acc[m]);
        acc[m] = MFMA16(ah, bl, acc[m]);
        acc[m] = MFMA16(al, bh, acc[m]);
    }
}
__device__ __forceinline__ void accToLds(const f32x4 (&acc)[6], float* sF, int gq, int cL){
    #pragma unroll
    for (int m=0;m<6;m++)
      #pragma unroll
      for (int q=0;q<4;q++)
        sF[(16*m+4*gq+q)*LSTR + cL] = acc[m][q];
}
// K=96 split GEMM, B from the LDS repack buffer
__device__ __forceinline__ void gemm96_lds(f32x4 (&acc)[6],
    const unsigned* __restrict__ ph, const unsigned* __restrict__ pl,
    int l, int gq, int cL, const float* sF)
{
    #pragma unroll
    for (int kb=0;kb<3;kb++){
        u32x4 Bh, Bl;
        #pragma unroll
        for (int p=0;p<4;p++){
            int f = 32*kb + 8*gq + 2*p;
            unsigned h, lo;
            split2(sF[f*LSTR + cL], sF[(f+1)*LSTR + cL], h, lo);
            Bh[p] = h; Bl[p] = lo;
        }
        gemm1(acc, ph, pl, 3, kb, l, Bh, Bl);
    }
}
// K=96 split GEMM, B gathered from a transposed global tensor [feat][64]
__device__ __forceinline__ void gemm96_glb(f32x4 (&acc)[6],
    const unsigned* __restrict__ ph, const unsigned* __restrict__ pl,
    int l, int gq, int col, const float* __restrict__ src_t)
{
    #pragma unroll
    for (int kb=0;kb<3;kb++){
        u32x4 Bh, Bl;
        #pragma unroll
        for (int p=0;p<4;p++){
            int f = 32*kb + 8*gq + 2*p;
            unsigned h, lo;
            split2(src_t[f*NN + col], src_t[(f+1)*NN + col], h, lo);
            Bh[p] = h; Bl[p] = lo;
        }
        gemm1(acc, ph, pl, 3, kb, l, Bh, Bl);
    }
}
// store acc transposed: dst[feat][col]
__device__ __forceinline__ void storeT16(const f32x4 (&acc)[6], float* __restrict__ dst,
                                         int gq, int col){
    #pragma unroll
    for (int m=0;m<6;m++)
      #pragma unroll
      for (int q=0;q<4;q++)
        dst[(16*m+4*gq+q)*NN + col] = acc[m][q];
}

// ---------------------------------------------------------------------------
// K0: pack all weights into MFMA A-frags. grid 255 x 64.
// ---------------------------------------------------------------------------
__global__ __launch_bounds__(64)
void k0_pack(const float* __restrict__ ne_W, const float* __restrict__ ee_W,
             const float* __restrict__ ep0_W1, const float* __restrict__ ep0_W2,
             const float* __restrict__ ep1_W1, const float* __restrict__ ep1_W2,
             const float* __restrict__ np_W1, const float* __restrict__ np_W2,
             const float* __restrict__ pred_W1, const float* __restrict__ pred_W2,
             unsigned* __restrict__ pk_e, unsigned* __restrict__ pk_n)
{
    int t = blockIdx.x, l = threadIdx.x;
    int cL = l & 15, gq = l >> 4;
    if (t < 108) {                         // edge-side, hi only
        int mat = t/18, tt = t%18, mt = tt/3, kb = tt%3;
        const float* mats[6] = { ep0_W1 + 2*HH*HH, ep0_W2, ep1_W1 + 2*HH*HH,
                                 ep1_W2, pred_W1, pred_W1 + HH*HH };
        const float* src = mats[mat];
        u32x4 d;
        #pragma unroll
        for (int p=0;p<4;p++){
            int k = 32*kb + 8*gq + 2*p;
            d[p] = pk2(src[k*HH + 16*mt + cL], src[(k+1)*HH + 16*mt + cL]);
        }
        *(u32x4*)&pk_e[mat*4608 + (mt*3+kb)*256 + l*4] = d;
    } else if (t < 111) {                  // pred_W2 zero-padded to 16 cols
        int kb = t - 108;
        u32x4 d;
        #pragma unroll
        for (int p=0;p<4;p++){
            int k = 32*kb + 8*gq + 2*p;
            float lo = (cL < 2) ? pred_W2[k*2 + cL]     : 0.f;
            float hi = (cL < 2) ? pred_W2[(k+1)*2 + cL] : 0.f;
            d[p] = pk2(lo, hi);
        }
        *(u32x4*)&pk_e[PE_P2 + kb*256 + l*4] = d;
    } else {
        int u = t - 111;
        if (u < 18) {                      // K=32 node mats: neW, Wr, Ws (hi+lo)
            int mat = u/6, mt = u%6;
            const float* srcs[3] = { ne_W, ee_W, ee_W + DD*HH };
            const float* src = srcs[mat];
            u32x4 dh, dl;
            #pragma unroll
            for (int p=0;p<4;p++){
                int k = 8*gq + 2*p;
                unsigned th, tl;
                split2(src[k*HH + 16*mt + cL], src[(k+1)*HH + 16*mt + cL], th, tl);
                dh[p] = th; dl[p] = tl;
            }
            int base = mat*3072 + mt*256 + l*4;
            *(u32x4*)&pk_n[base]        = dh;
            *(u32x4*)&pk_n[base + 1536] = dl;
        } else {                           // K=96 node mats (hi+lo)
            int u2 = u-18, mat = u2/18, tt = u2%18, mt = tt/3, kb = tt%3;
            u32x4 dh, dl;
            #pragma unroll
            for (int p=0;p<4;p++){
                int k = 32*kb + 8*gq + 2*p, col = 16*mt + cL;
                float v0, v1;
                if (mat == 2) {            // Wn12 = Wn1 + Wn2
                    v0 = np_W1[k*HH+col]     + np_W1[(HH+k)*HH+col];
                    v1 = np_W1[(k+1)*HH+col] + np_W1[(HH+k+1)*HH+col];
                } else {
                    const float* src = (mat==0) ? ep0_W1
                                     : (mat==1) ? ep0_W1 + HH*HH
                                     : (mat==3) ? np_W1 + 2*HH*HH
                                     : (mat==4) ? np_W2
                                     : (mat==5) ? ep1_W1
                                     :            ep1_W1 + HH*HH;
                    v0 = src[k*HH+col]; v1 = src[(k+1)*HH+col];
                }
                unsigned th, tl;
                split2(v0, v1, th, tl);
                dh[p] = th; dl[p] = tl;
            }
            int base = PN_ER0 + mat*9216 + (mt*3+kb)*256 + l*4;
            *(u32x4*)&pk_n[base]        = dh;
            *(u32x4*)&pk_n[base + 4608] = dl;
        }
    }
}

// ---------------------------------------------------------------------------
// K1: node encode + step-0 projections via split-MFMA. grid 128 x 64.
// block = (br, chunk): 16 rows per wave — 4x more latency chains, 4x shorter.
// ---------------------------------------------------------------------------
__global__ __launch_bounds__(64)
void k1_node(const float* __restrict__ node_rep,
             const float* __restrict__ ne_b, const float* __restrict__ ee_b,
             const float* __restrict__ ep0_b1,
             const unsigned* __restrict__ pk_n,
             float* __restrict__ wr_t, float* __restrict__ ws_t,
             float* __restrict__ ner0_t, float* __restrict__ nes0_t,
             float* __restrict__ enc_t)
{
    int blk = blockIdx.x, l = threadIdx.x;
    int br = blk >> 2, chunk = blk & 3;
    int b = br >> 3, r = br & 7;
    int cL = l & 15, gq = l >> 4;
    int col = 16*chunk + cL;
    __shared__ __align__(16) float sF[HH*LSTR];
    size_t brb = (size_t)br * HH * NN;

    // node_rep B-frag (K=32)
    u32x4 nBh, nBl;
    #pragma unroll
    for (int p=0;p<4;p++){
        int k = 8*gq + 2*p;
        const float* s = node_rep + ((size_t)((b*NN+col)*RR + r))*DD + k;
        unsigned h, lo;
        split2(s[0], s[1], h, lo);
        nBh[p] = h; nBl[p] = lo;
    }

    f32x4 acc[6];

    // enc = relu(node @ neW + ne_b)
    cinit6(acc, ne_b, gq);
    gemm1(acc, pk_n+PN_NEW, pk_n+PN_NEW+1536, 1, 0, l, nBh, nBl);
    relu6(acc);
    storeT16(acc, enc_t + brb, gq, col);
    accToLds(acc, sF, gq, cL);
    __syncthreads();

    // ner0 = enc @ Er0 + ep0_b1
    cinit6(acc, ep0_b1, gq);
    gemm96_lds(acc, pk_n+PN_ER0, pk_n+PN_ER0+4608, l, gq, cL, sF);
    storeT16(acc, ner0_t + brb, gq, col);

    // nes0 = enc @ Es0
    cinit6z(acc);
    gemm96_lds(acc, pk_n+PN_ES0, pk_n+PN_ES0+4608, l, gq, cL, sF);
    storeT16(acc, nes0_t + brb, gq, col);

    // wr' = node @ Wr + ee_b
    cinit6(acc, ee_b, gq);
    gemm1(acc, pk_n+PN_WR, pk_n+PN_WR+1536, 1, 0, l, nBh, nBl);
    storeT16(acc, wr_t + brb, gq, col);

    // ws = node @ Ws
    cinit6z(acc);
    gemm1(acc, pk_n+PN_WS, pk_n+PN_WS+1536, 1, 0, l, nBh, nBl);
    storeT16(acc, ws_t + brb, gq, col);
}

// ---------------------------------------------------------------------------
// K2: edge prop step 0 via MFMA (plain bf16). 1 wave per g. (unchanged)
// ---------------------------------------------------------------------------
__global__ __launch_bounds__(64)
void k2_edge0(const float* __restrict__ wr_t, const float* __restrict__ ws_t,
              const float* __restrict__ ner0_t, const float* __restrict__ nes0_t,
              const unsigned* __restrict__ pk_e,
              const float* __restrict__ ep0_b2,
              unsigned* __restrict__ ee0f, float* __restrict__ agg_t)
{
    int g = blockIdx.x, l = threadIdx.x;
    int b = g >> 9, r = g & 7, i = (g >> 3) & 63;
    int cL = l & 15, gq = l >> 4;
    size_t brb = (size_t)(b*RR + r)*HH*NN;
    const float* wrt = wr_t   + brb;
    const float* nrt = ner0_t + brb;
    const float* wst = ws_t   + brb;
    const float* nst = nes0_t + brb;
    const unsigned* Ae = pk_e + PE_EE0;
    const unsigned* Aw = pk_e + PE_W20;
    __shared__ __align__(16) unsigned sB[3072];

    // edge_enc B-frags
    u32x4 ee[3][4];
    #pragma unroll
    for (int kb=0;kb<3;kb++)
      #pragma unroll
      for (int n=0;n<4;n++)
        #pragma unroll
        for (int p=0;p<4;p++){
            int h = 32*kb + 8*gq + 2*p;
            int j = 16*n + cL;
            float a0 = fmaxf(wrt[h*NN + i]     + wst[h*NN + j],     0.f);
            float a1 = fmaxf(wrt[(h+1)*NN + i] + wst[(h+1)*NN + j], 0.f);
            ee[kb][n][p] = pk2(a0, a1);
        }

    f32x4 acc[6][4];
    #pragma unroll
    for (int m=0;m<6;m++)
      #pragma unroll
      for (int q=0;q<4;q++){
        int c = 16*m + 4*gq + q;
        float nr = nrt[c*NN + i];
        #pragma unroll
        for (int n=0;n<4;n++) acc[m][n][q] = nr + nst[c*NN + 16*n + cL];
      }

    // GEMM1: t0 = Ee0^T @ edge_enc^T
    #pragma unroll
    for (int kb=0;kb<3;kb++){
        bf16x8 A[6];
        #pragma unroll
        for (int m=0;m<6;m++) A[m] = __builtin_bit_cast(bf16x8, *(const u32x4*)&Ae[((m*3+kb)*64 + l)*4]);
        #pragma unroll
        for (int n=0;n<4;n++){
            bf16x8 Bf = __builtin_bit_cast(bf16x8, ee[kb][n]);
            #pragma unroll
            for (int m=0;m<6;m++) acc[m][n] = MFMA16(A[m], Bf, acc[m][n]);
        }
    }

    // relu + repack -> LDS B-frags (plain bf16)
    #pragma unroll
    for (int m=0;m<6;m++)
      #pragma unroll
      for (int n=0;n<4;n++){
        float v0 = fmaxf(acc[m][n][0],0.f), v1 = fmaxf(acc[m][n][1],0.f);
        float v2 = fmaxf(acc[m][n][2],0.f), v3 = fmaxf(acc[m][n][3],0.f);
        int gd = 2*(m&1) + (gq>>1);
        int dw = (((m>>1)*4 + n)*64 + 16*gd + cL)*4 + 2*(gq&1);
        sB[dw]   = pk2(v0,v1);
        sB[dw+1] = pk2(v2,v3);
      }

    #pragma unroll
    for (int m=0;m<6;m++)
      #pragma unroll
      for (int q=0;q<4;q++){
        float bv = ep0_b2[16*m + 4*gq + q];
        #pragma unroll
        for (int n=0;n<4;n++) acc[m][n][q] = bv;
      }

    // GEMM2: ee0 = W20^T @ t0^T
    #pragma unroll
    for (int kb=0;kb<3;kb++){
        bf16x8 A[6];
        #pragma unroll
        for (int m=0;m<6;m++) A[m] = __builtin_bit_cast(bf16x8, *(const u32x4*)&Aw[((m*3+kb)*64 + l)*4]);
        #pragma unroll
        for (int n=0;n<4;n++){
            bf16x8 Bf = __builtin_bit_cast(bf16x8, *(const u32x4*)&sB[((kb*4+n)*64 + l)*4]);
            #pragma unroll
            for (int m=0;m<6;m++) acc[m][n] = MFMA16(A[m], Bf, acc[m][n]);
        }
    }

    #pragma unroll
    for (int m=0;m<6;m++)
      #pragma unroll
      for (int n=0;n<4;n++)
        #pragma unroll
        for (int q=0;q<4;q++) acc[m][n][q] = fmaxf(acc[m][n][q], 0.f);

    // store ee0 frags (B-layout bf16) + agg reduce (transposed write)
    unsigned* eo = ee0f + (size_t)g*3072;
    #pragma unroll
    for (int m=0;m<6;m++)
      #pragma unroll
      for (int n=0;n<4;n++){
        int gd = 2*(m&1) + (gq>>1);
        int dw = (((m>>1)*4 + n)*64 + 16*gd + cL)*4 + 2*(gq&1);
        eo[dw]   = pk2(acc[m][n][0], acc[m][n][1]);
        eo[dw+1] = pk2(acc[m][n][2], acc[m][n][3]);
      }
    #pragma unroll
    for (int m=0;m<6;m++)
      #pragma unroll
      for (int q=0;q<4;q++){
        float s = acc[m][0][q] + acc[m][1][q] + acc[m][2][q] + acc[m][3][q];
        s += __shfl_xor(s, 1);
        s += __shfl_xor(s, 2);
        s += __shfl_xor(s, 4);
        s += __shfl_xor(s, 8);
        if (cL == 0) agg_t[brb + (16*m + 4*gq + q)*NN + i] = s;
      }
}

// ---------------------------------------------------------------------------
// K3: node update + step-1 projections via split-MFMA. grid 128 x 64.
// ---------------------------------------------------------------------------
__global__ __launch_bounds__(64)
void k3_node(const float* __restrict__ enc_t_g, const float* __restrict__ agg_t_g,
             const float* __restrict__ np_b1, const float* __restrict__ np_b2,
             const float* __restrict__ ep1_b1,
             const unsigned* __restrict__ pk_n,
             float* __restrict__ ner1_t, float* __restrict__ nes1_t)
{
    int blk = blockIdx.x, l = threadIdx.x;
    int br = blk >> 2, chunk = blk & 3;
    int cL = l & 15, gq = l >> 4;
    int col = 16*chunk + cL;
    __shared__ __align__(16) float sF[HH*LSTR];
    size_t brb = (size_t)br * HH * NN;
    const float* enc_t = enc_t_g + brb;
    const float* agg_t = agg_t_g + brb;

    f32x4 acc[6];

    // t = relu(enc @ Wn12 + agg @ Wn3 + np_b1)
    cinit6(acc, np_b1, gq);
    gemm96_glb(acc, pk_n+PN_WN12, pk_n+PN_WN12+4608, l, gq, col, enc_t);
    gemm96_glb(acc, pk_n+PN_WN3,  pk_n+PN_WN3+4608,  l, gq, col, agg_t);
    relu6(acc);
    accToLds(acc, sF, gq, cL);
    __syncthreads();

    // ne1 = relu(t @ npW2 + np_b2)
    cinit6(acc, np_b2, gq);
    gemm96_lds(acc, pk_n+PN_NPW2, pk_n+PN_NPW2+4608, l, gq, cL, sF);
    relu6(acc);
    __syncthreads();                 // drain reads of t before overwrite
    accToLds(acc, sF, gq, cL);
    __syncthreads();

    // ner1 = ne1 @ Er1 + ep1_b1
    cinit6(acc, ep1_b1, gq);
    gemm96_lds(acc, pk_n+PN_ER1, pk_n+PN_ER1+4608, l, gq, cL, sF);
    storeT16(acc, ner1_t + brb, gq, col);

    // nes1 = ne1 @ Es1
    cinit6z(acc);
    gemm96_lds(acc, pk_n+PN_ES1, pk_n+PN_ES1+4608, l, gq, cL, sF);
    storeT16(acc, nes1_t + brb, gq, col);
}

// ---------------------------------------------------------------------------
// K4: edge prop step 1 + prediction head via MFMA. 1 wave per g. (unchanged)
// ---------------------------------------------------------------------------
__global__ __launch_bounds__(64)
void k4_edge1(const float* __restrict__ wr_t, const float* __restrict__ ws_t,
              const float* __restrict__ ner1_t, const float* __restrict__ nes1_t,
              const unsigned* __restrict__ pk_e,
              const unsigned* __restrict__ ee0f,
              const float* __restrict__ ep1_b2,
              const float* __restrict__ pred_b1, const float* __restrict__ pred_b2,
              float* __restrict__ out)
{
    int g = blockIdx.x, l = threadIdx.x;
    int b = g >> 9, i = (g >> 3) & 63, r = g & 7;
    int cL = l & 15, gq = l >> 4;
    size_t brb = (size_t)(b*RR + r)*HH*NN;
    const float* wrt = wr_t   + brb;
    const float* wst = ws_t   + brb;
    const float* nrt = ner1_t + brb;
    const float* nst = nes1_t + brb;
    const unsigned* Ae1 = pk_e + PE_EE1;
    const unsigned* Aw1 = pk_e + PE_W21;
    const unsigned* Ape = pk_e + PE_PE;
    const unsigned* Apc = pk_e + PE_PC;
    const unsigned* Ap2 = pk_e + PE_P2;
    __shared__ __align__(16) unsigned sB[3072];

    const u32x4* e0p = (const u32x4*)ee0f + (size_t)g*768;
    u32x4 bf0[3][4];
    #pragma unroll
    for (int kb=0;kb<3;kb++)
      #pragma unroll
      for (int n=0;n<4;n++) bf0[kb][n] = e0p[(kb*4+n)*64 + l];

    f32x4 acc[6][4];
    #pragma unroll
    for (int m=0;m<6;m++)
      #pragma unroll
      for (int q=0;q<4;q++){
        int c = 16*m + 4*gq + q;
        float nr = nrt[c*NN + i];
        #pragma unroll
        for (int n=0;n<4;n++) acc[m][n][q] = nr + nst[c*NN + 16*n + cL];
      }

    // GEMM1: t1 = Ee1^T @ ee0^T
    #pragma unroll
    for (int kb=0;kb<3;kb++){
        bf16x8 A[6];
        #pragma unroll
        for (int m=0;m<6;m++) A[m] = __builtin_bit_cast(bf16x8, *(const u32x4*)&Ae1[((m*3+kb)*64 + l)*4]);
        #pragma unroll
        for (int n=0;n<4;n++){
            bf16x8 Bf = __builtin_bit_cast(bf16x8, bf0[kb][n]);
            #pragma unroll
            for (int m=0;m<6;m++) acc[m][n] = MFMA16(A[m], Bf, acc[m][n]);
        }
    }

    // relu + repack t1 -> LDS
    #pragma unroll
    for (int m=0;m<6;m++)
      #pragma unroll
      for (int n=0;n<4;n++){
        float v0 = fmaxf(acc[m][n][0],0.f), v1 = fmaxf(acc[m][n][1],0.f);
        float v2 = fmaxf(acc[m][n][2],0.f), v3 = fmaxf(acc[m][n][3],0.f);
        int gd = 2*(m&1) + (gq>>1);
        int dw = (((m>>1)*4 + n)*64 + 16*gd + cL)*4 + 2*(gq&1);
        sB[dw]   = pk2(v0,v1);
        sB[dw+1] = pk2(v2,v3);
      }

    #pragma unroll
    for (int m=0;m<6;m++)
      #pragma unroll
      for (int q=0;q<4;q++){
        float bv = ep1_b2[16*m + 4*gq + q];
        #pragma unroll
        for (int n=0;n<4;n++) acc[m][n][q] = bv;
      }

    // GEMM2: ee1 = W21^T @ t1^T
    #pragma unroll
    for (int kb=0;kb<3;kb++){
        bf16x8 A[6];
        #pragma unroll
        for (int m=0;m<6;m++) A[m] = __builtin_bit_cast(bf16x8, *(const u32x4*)&Aw1[((m*3+kb)*64 + l)*4]);
        #pragma unroll
        for (int n=0;n<4;n++){
            bf16x8 Bf = __builtin_bit_cast(bf16x8, *(const u32x4*)&sB[((kb*4+n)*64 + l)*4]);
            #pragma unroll
            for (int m=0;m<6;m++) acc[m][n] = MFMA16(A[m], Bf, acc[m][n]);
        }
    }

    // relu + repack ee1 -> LDS
    #pragma unroll
    for (int m=0;m<6;m++)
      #pragma unroll
      for (int n=0;n<4;n++){
        float v0 = fmaxf(acc[m][n][0],0.f), v1 = fmaxf(acc[m][n][1],0.f);
        float v2 = fmaxf(acc[m][n][2],0.f), v3 = fmaxf(acc[m][n][3],0.f);
        int gd = 2*(m&1) + (gq>>1);
        int dw = (((m>>1)*4 + n)*64 + 16*gd + cL)*4 + 2*(gq&1);
        sB[dw]   = pk2(v0,v1);
        sB[dw+1] = pk2(v2,v3);
      }

    #pragma unroll
    for (int m=0;m<6;m++)
      #pragma unroll
      for (int q=0;q<4;q++){
        float bv = pred_b1[16*m + 4*gq + q];
        #pragma unroll
        for (int n=0;n<4;n++) acc[m][n][q] = bv;
      }

    // GEMM3: += Pe^T @ ee1^T
    #pragma unroll
    for (int kb=0;kb<3;kb++){
        bf16x8 A[6];
        #pragma unroll
        for (int m=0;m<6;m++) A[m] = __builtin_bit_cast(bf16x8, *(const u32x4*)&Ape[((m*3+kb)*64 + l)*4]);
        #pragma unroll
        for (int n=0;n<4;n++){
            bf16x8 Bf = __builtin_bit_cast(bf16x8, *(const u32x4*)&sB[((kb*4+n)*64 + l)*4]);
            #pragma unroll
            for (int m=0;m<6;m++) acc[m][n] = MFMA16(A[m], Bf, acc[m][n]);
        }
    }

    // rebuild edge_enc B-frags
    u32x4 ee[3][4];
    #pragma unroll
    for (int kb=0;kb<3;kb++)
      #pragma unroll
      for (int n=0;n<4;n++)
        #pragma unroll
        for (int p=0;p<4;p++){
            int h = 32*kb + 8*gq + 2*p;
            int j = 16*n + cL;
            float a0 = fmaxf(wrt[h*NN + i]     + wst[h*NN + j],     0.f);
            float a1 = fmaxf(wrt[(h+1)*NN + i] + wst[(h+1)*NN + j], 0.f);
            ee[kb][n][p] = pk2(a0, a1);
        }

    // GEMM4: += Pc^T @ edge_enc^T
    #pragma unroll
    for (int kb=0;kb<3;kb++){
        bf16x8 A[6];
        #pragma unroll
        for (int m=0;m<6;m++) A[m] = __builtin_bit_cast(bf16x8, *(const u32x4*)&Apc[((m*3+kb)*64 + l)*4]);
        #pragma unroll
        for (int n=0;n<4;n++){
            bf16x8 Bf = __builtin_bit_cast(bf16x8, ee[kb][n]);
            #pragma unroll
            for (int m=0;m<6;m++) acc[m][n] = MFMA16(A[m], Bf, acc[m][n]);
        }
    }

    // relu + repack tp -> LDS
    #pragma unroll
    for (int m=0;m<6;m++)
      #pragma unroll
      for (int n=0;n<4;n++){
        float v0 = fmaxf(acc[m][n][0],0.f), v1 = fmaxf(acc[m][n][1],0.f);
        float v2 = fmaxf(acc[m][n][2],0.f), v3 = fmaxf(acc[m][n][3],0.f);
        int gd = 2*(m&1) + (gq>>1);
        int dw = (((m>>1)*4 + n)*64 + 16*gd + cL)*4 + 2*(gq&1);
        sB[dw]   = pk2(v0,v1);
        sB[dw+1] = pk2(v2,v3);
      }

    // GEMM5: out = P2^T @ tp^T (rows 0,1 valid)
    f32x4 c5[4];
    #pragma unroll
    for (int n=0;n<4;n++){
        c5[n][0] = (gq == 0) ? pred_b2[0] : 0.f;
        c5[n][1] = (gq == 0) ? pred_b2[1] : 0.f;
        c5[n][2] = 0.f; c5[n][3] = 0.f;
    }
    #pragma unroll
    for (int kb=0;kb<3;kb++){
        bf16x8 A2 = __builtin_bit_cast(bf16x8, *(const u32x4*)&Ap2[(kb*64 + l)*4]);
        #pragma unroll
        for (int n=0;n<4;n++){
            bf16x8 Bf = __builtin_bit_cast(bf16x8, *(const u32x4*)&sB[((kb*4+n)*64 + l)*4]);
            c5[n] = MFMA16(A2, Bf, c5[n]);
        }
    }
    if (gq == 0) {
        float2* o2 = (float2*)out;
        #pragma unroll
        for (int n=0;n<4;n++){
            size_t j = 16*n + cL;
            o2[(((size_t)(b*NN + i))*NN + j)*RR + r] = make_float2(c5[n][0], c5[n][1]);
        }
    }
}

// ---------------------------------------------------------------------------
extern "C" void kernel_launch(void* const* d_in, const int* in_sizes, int n_in,
                              void* d_out, int out_size, void* d_ws, size_t ws_size,
                              hipStream_t stream)
{
    const float* node_rep = (const float*)d_in[0];
    const float* ne_W    = (const float*)d_in[1];
    const float* ne_b    = (const float*)d_in[2];
    const float* ee_W    = (const float*)d_in[3];
    const float* ee_b    = (const float*)d_in[4];
    const float* np_W1   = (const float*)d_in[5];
    const float* np_b1   = (const float*)d_in[6];
    const float* np_W2   = (const float*)d_in[7];
    const float* np_b2   = (const float*)d_in[8];
    const float* ep0_W1  = (const float*)d_in[9];
    const float* ep0_b1  = (const float*)d_in[10];
    const float* ep0_W2  = (const float*)d_in[11];
    const float* ep0_b2  = (const float*)d_in[12];
    const float* ep1_W1  = (const float*)d_in[13];
    const float* ep1_b1  = (const float*)d_in[14];
    const float* ep1_W2  = (const float*)d_in[15];
    const float* ep1_b2  = (const float*)d_in[16];
    const float* pred_W1 = (const float*)d_in[17];
    const float* pred_b1 = (const float*)d_in[18];
    const float* pred_W2 = (const float*)d_in[19];
    const float* pred_b2 = (const float*)d_in[20];
    float* wsf = (float*)d_ws;
    float* out = (float*)d_out;

    float* wr_t   = wsf + OFF_WR_T;
    float* ws_t   = wsf + OFF_WS_T;
    float* ner0_t = wsf + OFF_NER0;
    float* nes0_t = wsf + OFF_NES0;
    float* ner1_t = wsf + OFF_NER1;
    float* nes1_t = wsf + OFF_NES1;
    float* enc_t  = wsf + OFF_ENCT;
    float* agg_t  = wsf + OFF_AGGT;
    unsigned* pk_e = (unsigned*)(wsf + OFF_PKE);
    unsigned* pk_n = (unsigned*)(wsf + OFF_PKN);
    unsigned* ee0f = (unsigned*)(wsf + OFF_EE0F);

    k0_pack<<<255, 64, 0, stream>>>(ne_W, ee_W, ep0_W1, ep0_W2, ep1_W1, ep1_W2,
                                    np_W1, np_W2, pred_W1, pred_W2, pk_e, pk_n);

    k1_node<<<128, 64, 0, stream>>>(node_rep, ne_b, ee_b, ep0_b1, pk_n,
                                    wr_t, ws_t, ner0_t, nes0_t, enc_t);

    k2_edge0<<<NGROUP, 64, 0, stream>>>(wr_t, ws_t, ner0_t, nes0_t, pk_e, ep0_b2,
                                        ee0f, agg_t);

    k3_node<<<128, 64, 0, stream>>>(enc_t, agg_t, np_b1, np_b2, ep1_b1, pk_n,
                                    ner1_t, nes1_t);

    k4_edge1<<<NGROUP, 64, 0, stream>>>(wr_t, ws_t, ner1_t, nes1_t, pk_e, ee0f,
                                        ep1_b2, pred_b1, pred_b2, out);
}

// Round 8
// 99.132 us; speedup vs baseline: 7.4945x; 1.0328x over previous
//
#include <hip/hip_runtime.h>
#include <hip/hip_bf16.h>

#define BB 4
#define NN 64
#define RR 8
#define DD 32
#define HH 96
#define NGROUP (BB*NN*RR)   // 2048
#define LSTR 17             // padded LDS stride (floats) for node repack buffer

// workspace float offsets — all node-side tensors transposed [b*8+r][feat][node]
#define OFF_WR_T  0
#define OFF_WS_T  196608
#define OFF_NER0  393216
#define OFF_NES0  589824
#define OFF_NER1  786432
#define OFF_NES1  983040
#define OFF_ENCT  1179648
#define OFF_AGGT  1376256
#define OFF_PKE   1572864      // edge-side packed weights (hi only), 28416 u32
#define OFF_PKN   1601280      // node-side packed weights (hi+lo), 73728 u32
#define OFF_EE0F  1675008      // ee0 in B-frag bf16 form, 2048*3072 u32

// pk_e u32 offsets (frag = 256 u32; 96x96 mat = 18 frags = 4608)
#define PE_EE0  0
#define PE_W20  4608
#define PE_EE1  9216
#define PE_W21  13824
#define PE_PE   18432
#define PE_PC   23040
#define PE_P2   27648
// pk_n u32 offsets (K=32 mats: 6 frags = 1536/part; K=96 mats: 4608/part; hi then lo)
#define PN_NEW  0
#define PN_WR   3072
#define PN_WS   6144
#define PN_ER0  9216
#define PN_ES0  18432
#define PN_WN12 27648
#define PN_WN3  36864
#define PN_NPW2 46080
#define PN_ER1  55296
#define PN_ES1  64512

typedef __attribute__((ext_vector_type(4))) float f32x4;
typedef __attribute__((ext_vector_type(8))) short bf16x8;
typedef __attribute__((ext_vector_type(4))) unsigned int u32x4;

__device__ __forceinline__ unsigned int pk2(float lo, float hi){
    unsigned short a = __builtin_bit_cast(unsigned short, __float2bfloat16(lo));
    unsigned short b = __builtin_bit_cast(unsigned short, __float2bfloat16(hi));
    return (unsigned)a | ((unsigned)b << 16);
}
// split v into bf16 hi + bf16 lo residual (x ~ hi + lo to ~2^-17 rel)
__device__ __forceinline__ void split2(float v0, float v1, unsigned &h, unsigned &lo){
    float h0 = __bfloat162float(__float2bfloat16(v0));
    float h1 = __bfloat162float(__float2bfloat16(v1));
    h  = pk2(v0, v1);
    lo = pk2(v0 - h0, v1 - h1);
}

#define MFMA16(A,B,C) __builtin_amdgcn_mfma_f32_16x16x32_bf16((A),(B),(C),0,0,0)

// ================= 16-row node-kernel helpers (acc[6], one 16-col chunk) ====
__device__ __forceinline__ void cinit6(f32x4 (&acc)[6], const float* __restrict__ bv, int gq){
    #pragma unroll
    for (int m=0;m<6;m++)
      #pragma unroll
      for (int q=0;q<4;q++) acc[m][q] = bv[16*m+4*gq+q];
}
__device__ __forceinline__ void cinit6z(f32x4 (&acc)[6]){
    #pragma unroll
    for (int m=0;m<6;m++)
      #pragma unroll
      for (int q=0;q<4;q++) acc[m][q] = 0.f;
}
__device__ __forceinline__ void relu6(f32x4 (&acc)[6]){
    #pragma unroll
    for (int m=0;m<6;m++)
      #pragma unroll
      for (int q=0;q<4;q++) acc[m][q] = fmaxf(acc[m][q], 0.f);
}
// one kb of split GEMM: acc += Ah@Bh + Ah@Bl + Al@Bh (6 m-tiles)
__device__ __forceinline__ void gemm1(f32x4 (&acc)[6],
    const unsigned* __restrict__ ph, const unsigned* __restrict__ pl,
    int nkb, int kb, int l, const u32x4 &Bh, const u32x4 &Bl)
{
    bf16x8 bh = __builtin_bit_cast(bf16x8, Bh);
    bf16x8 bl = __builtin_bit_cast(bf16x8, Bl);
    #pragma unroll
    for (int m=0;m<6;m++){
        bf16x8 ah = __builtin_bit_cast(bf16x8, *(const u32x4*)&ph[(m*nkb+kb)*256 + l*4]);
        bf16x8 al = __builtin_bit_cast(bf16x8, *(const u32x4*)&pl[(m*nkb+kb)*256 + l*4]);
        acc[m] = MFMA16(ah, bh, acc[m]);
        acc[m] = MFMA16(ah, bl, acc[m]);
        acc[m] = MFMA16(al, bh, acc[m]);
    }
}
__device__ __forceinline__ void accToLds(const f32x4 (&acc)[6], float* sF, int gq, int cL){
    #pragma unroll
    for (int m=0;m<6;m++)
      #pragma unroll
      for (int q=0;q<4;q++)
        sF[(16*m+4*gq+q)*LSTR + cL] = acc[m][q];
}
// K=96 split GEMM, B from the LDS repack buffer
__device__ __forceinline__ void gemm96_lds(f32x4 (&acc)[6],
    const unsigned* __restrict__ ph, const unsigned* __restrict__ pl,
    int l, int gq, int cL, const float* sF)
{
    #pragma unroll
    for (int kb=0;kb<3;kb++){
        u32x4 Bh, Bl;
        #pragma unroll
        for (int p=0;p<4;p++){
            int f = 32*kb + 8*gq + 2*p;
            unsigned h, lo;
            split2(sF[f*LSTR + cL], sF[(f+1)*LSTR + cL], h, lo);
            Bh[p] = h; Bl[p] = lo;
        }
        gemm1(acc, ph, pl, 3, kb, l, Bh, Bl);
    }
}
// K=96 split GEMM, B gathered from a transposed global tensor [feat][64]
__device__ __forceinline__ void gemm96_glb(f32x4 (&acc)[6],
    const unsigned* __restrict__ ph, const unsigned* __restrict__ pl,
    int l, int gq, int col, const float* __restrict__ src_t)
{
    #pragma unroll
    for (int kb=0;kb<3;kb++){
        u32x4 Bh, Bl;
        #pragma unroll
        for (int p=0;p<4;p++){
            int f = 32*kb + 8*gq + 2*p;
            unsigned h, lo;
            split2(src_t[f*NN + col], src_t[(f+1)*NN + col], h, lo);
            Bh[p] = h; Bl[p] = lo;
        }
        gemm1(acc, ph, pl, 3, kb, l, Bh, Bl);
    }
}
// store acc transposed: dst[feat][col]
__device__ __forceinline__ void storeT16(const f32x4 (&acc)[6], float* __restrict__ dst,
                                         int gq, int col){
    #pragma unroll
    for (int m=0;m<6;m++)
      #pragma unroll
      for (int q=0;q<4;q++)
        dst[(16*m+4*gq+q)*NN + col] = acc[m][q];
}

// ================= edge-kernel helpers (2 waves/block, 3 m-tiles/wave) ======
__device__ __forceinline__ void einit_b(f32x4 (&acc)[3][4], const float* __restrict__ bv,
                                        int mBase, int gq){
    #pragma unroll
    for (int mi=0;mi<3;mi++)
      #pragma unroll
      for (int q=0;q<4;q++){
        float x = bv[16*(mBase+mi)+4*gq+q];
        #pragma unroll
        for (int n=0;n<4;n++) acc[mi][n][q] = x;
      }
}
// one kb: acc[mi][n] += A[mBase+mi][kb] @ Bk[n]
__device__ __forceinline__ void egemm_kb(f32x4 (&acc)[3][4],
    const unsigned* __restrict__ Apk, int mBase, int kb, int l, const u32x4 (&Bk)[4])
{
    #pragma unroll
    for (int mi=0;mi<3;mi++){
        bf16x8 a = __builtin_bit_cast(bf16x8, *(const u32x4*)&Apk[(((mBase+mi)*3+kb)*64 + l)*4]);
        #pragma unroll
        for (int n=0;n<4;n++){
            bf16x8 bf = __builtin_bit_cast(bf16x8, Bk[n]);
            acc[mi][n] = MFMA16(a, bf, acc[mi][n]);
        }
    }
}
// build edge_enc B-frags for one kb
__device__ __forceinline__ void build_ee_kb(u32x4 (&Bk)[4],
    const float* __restrict__ wrt, const float* __restrict__ wst,
    int i, int kb, int gq, int cL)
{
    #pragma unroll
    for (int n=0;n<4;n++)
      #pragma unroll
      for (int p=0;p<4;p++){
        int h = 32*kb + 8*gq + 2*p;
        int j = 16*n + cL;
        float a0 = fmaxf(wrt[h*NN + i]     + wst[h*NN + j],     0.f);
        float a1 = fmaxf(wrt[(h+1)*NN + i] + wst[(h+1)*NN + j], 0.f);
        Bk[n][p] = pk2(a0, a1);
      }
}
__device__ __forceinline__ void load_sB_kb(u32x4 (&Bk)[4], const unsigned* sB, int kb, int l){
    #pragma unroll
    for (int n=0;n<4;n++) Bk[n] = *(const u32x4*)&sB[((kb*4+n)*64 + l)*4];
}
// repack this wave's m-half (with relu) into B-frag LDS layout
__device__ __forceinline__ void repack_half(const f32x4 (&acc)[3][4], unsigned* sB,
                                            int mBase, int gq, int cL)
{
    #pragma unroll
    for (int mi=0;mi<3;mi++){
      int m = mBase+mi;
      #pragma unroll
      for (int n=0;n<4;n++){
        float v0 = fmaxf(acc[mi][n][0],0.f), v1 = fmaxf(acc[mi][n][1],0.f);
        float v2 = fmaxf(acc[mi][n][2],0.f), v3 = fmaxf(acc[mi][n][3],0.f);
        int gd = 2*(m&1) + (gq>>1);
        int dw = (((m>>1)*4 + n)*64 + 16*gd + cL)*4 + 2*(gq&1);
        sB[dw]   = pk2(v0,v1);
        sB[dw+1] = pk2(v2,v3);
      }
    }
}

// ---------------------------------------------------------------------------
// K0: pack all weights into MFMA A-frags. grid 255 x 64.
// ---------------------------------------------------------------------------
__global__ __launch_bounds__(64)
void k0_pack(const float* __restrict__ ne_W, const float* __restrict__ ee_W,
             const float* __restrict__ ep0_W1, const float* __restrict__ ep0_W2,
             const float* __restrict__ ep1_W1, const float* __restrict__ ep1_W2,
             const float* __restrict__ np_W1, const float* __restrict__ np_W2,
             const float* __restrict__ pred_W1, const float* __restrict__ pred_W2,
             unsigned* __restrict__ pk_e, unsigned* __restrict__ pk_n)
{
    int t = blockIdx.x, l = threadIdx.x;
    int cL = l & 15, gq = l >> 4;
    if (t < 108) {                         // edge-side, hi only
        int mat = t/18, tt = t%18, mt = tt/3, kb = tt%3;
        const float* mats[6] = { ep0_W1 + 2*HH*HH, ep0_W2, ep1_W1 + 2*HH*HH,
                                 ep1_W2, pred_W1, pred_W1 + HH*HH };
        const float* src = mats[mat];
        u32x4 d;
        #pragma unroll
        for (int p=0;p<4;p++){
            int k = 32*kb + 8*gq + 2*p;
            d[p] = pk2(src[k*HH + 16*mt + cL], src[(k+1)*HH + 16*mt + cL]);
        }
        *(u32x4*)&pk_e[mat*4608 + (mt*3+kb)*256 + l*4] = d;
    } else if (t < 111) {                  // pred_W2 zero-padded to 16 cols
        int kb = t - 108;
        u32x4 d;
        #pragma unroll
        for (int p=0;p<4;p++){
            int k = 32*kb + 8*gq + 2*p;
            float lo = (cL < 2) ? pred_W2[k*2 + cL]     : 0.f;
            float hi = (cL < 2) ? pred_W2[(k+1)*2 + cL] : 0.f;
            d[p] = pk2(lo, hi);
        }
        *(u32x4*)&pk_e[PE_P2 + kb*256 + l*4] = d;
    } else {
        int u = t - 111;
        if (u < 18) {                      // K=32 node mats: neW, Wr, Ws (hi+lo)
            int mat = u/6, mt = u%6;
            const float* srcs[3] = { ne_W, ee_W, ee_W + DD*HH };
            const float* src = srcs[mat];
            u32x4 dh, dl;
            #pragma unroll
            for (int p=0;p<4;p++){
                int k = 8*gq + 2*p;
                unsigned th, tl;
                split2(src[k*HH + 16*mt + cL], src[(k+1)*HH + 16*mt + cL], th, tl);
                dh[p] = th; dl[p] = tl;
            }
            int base = mat*3072 + mt*256 + l*4;
            *(u32x4*)&pk_n[base]        = dh;
            *(u32x4*)&pk_n[base + 1536] = dl;
        } else {                           // K=96 node mats (hi+lo)
            int u2 = u-18, mat = u2/18, tt = u2%18, mt = tt/3, kb = tt%3;
            u32x4 dh, dl;
            #pragma unroll
            for (int p=0;p<4;p++){
                int k = 32*kb + 8*gq + 2*p, col = 16*mt + cL;
                float v0, v1;
                if (mat == 2) {            // Wn12 = Wn1 + Wn2
                    v0 = np_W1[k*HH+col]     + np_W1[(HH+k)*HH+col];
                    v1 = np_W1[(k+1)*HH+col] + np_W1[(HH+k+1)*HH+col];
                } else {
                    const float* src = (mat==0) ? ep0_W1
                                     : (mat==1) ? ep0_W1 + HH*HH
                                     : (mat==3) ? np_W1 + 2*HH*HH
                                     : (mat==4) ? np_W2
                                     : (mat==5) ? ep1_W1
                                     :            ep1_W1 + HH*HH;
                    v0 = src[k*HH+col]; v1 = src[(k+1)*HH+col];
                }
                unsigned th, tl;
                split2(v0, v1, th, tl);
                dh[p] = th; dl[p] = tl;
            }
            int base = PN_ER0 + mat*9216 + (mt*3+kb)*256 + l*4;
            *(u32x4*)&pk_n[base]        = dh;
            *(u32x4*)&pk_n[base + 4608] = dl;
        }
    }
}

// ---------------------------------------------------------------------------
// K1: node encode + step-0 projections via split-MFMA. grid 128 x 64.
// ---------------------------------------------------------------------------
__global__ __launch_bounds__(64)
void k1_node(const float* __restrict__ node_rep,
             const float* __restrict__ ne_b, const float* __restrict__ ee_b,
             const float* __restrict__ ep0_b1,
             const unsigned* __restrict__ pk_n,
             float* __restrict__ wr_t, float* __restrict__ ws_t,
             float* __restrict__ ner0_t, float* __restrict__ nes0_t,
             float* __restrict__ enc_t)
{
    int blk = blockIdx.x, l = threadIdx.x;
    int br = blk >> 2, chunk = blk & 3;
    int b = br >> 3, r = br & 7;
    int cL = l & 15, gq = l >> 4;
    int col = 16*chunk + cL;
    __shared__ __align__(16) float sF[HH*LSTR];
    size_t brb = (size_t)br * HH * NN;

    // node_rep B-frag (K=32)
    u32x4 nBh, nBl;
    #pragma unroll
    for (int p=0;p<4;p++){
        int k = 8*gq + 2*p;
        const float* s = node_rep + ((size_t)((b*NN+col)*RR + r))*DD + k;
        unsigned h, lo;
        split2(s[0], s[1], h, lo);
        nBh[p] = h; nBl[p] = lo;
    }

    f32x4 acc[6];

    // enc = relu(node @ neW + ne_b)
    cinit6(acc, ne_b, gq);
    gemm1(acc, pk_n+PN_NEW, pk_n+PN_NEW+1536, 1, 0, l, nBh, nBl);
    relu6(acc);
    storeT16(acc, enc_t + brb, gq, col);
    accToLds(acc, sF, gq, cL);
    __syncthreads();

    // ner0 = enc @ Er0 + ep0_b1
    cinit6(acc, ep0_b1, gq);
    gemm96_lds(acc, pk_n+PN_ER0, pk_n+PN_ER0+4608, l, gq, cL, sF);
    storeT16(acc, ner0_t + brb, gq, col);

    // nes0 = enc @ Es0
    cinit6z(acc);
    gemm96_lds(acc, pk_n+PN_ES0, pk_n+PN_ES0+4608, l, gq, cL, sF);
    storeT16(acc, nes0_t + brb, gq, col);

    // wr' = node @ Wr + ee_b
    cinit6(acc, ee_b, gq);
    gemm1(acc, pk_n+PN_WR, pk_n+PN_WR+1536, 1, 0, l, nBh, nBl);
    storeT16(acc, wr_t + brb, gq, col);

    // ws = node @ Ws
    cinit6z(acc);
    gemm1(acc, pk_n+PN_WS, pk_n+PN_WS+1536, 1, 0, l, nBh, nBl);
    storeT16(acc, ws_t + brb, gq, col);
}

// ---------------------------------------------------------------------------
// K2: edge prop step 0 via MFMA. block = 128 (2 waves), wave w owns m-tiles
// 3w..3w+2. One barrier (t0 handoff through LDS B-frags).
// ---------------------------------------------------------------------------
__global__ __launch_bounds__(128)
void k2_edge0(const float* __restrict__ wr_t, const float* __restrict__ ws_t,
              const float* __restrict__ ner0_t, const float* __restrict__ nes0_t,
              const unsigned* __restrict__ pk_e,
              const float* __restrict__ ep0_b2,
              unsigned* __restrict__ ee0f, float* __restrict__ agg_t)
{
    int g = blockIdx.x, tid = threadIdx.x;
    int w = tid >> 6, l = tid & 63;
    int b = g >> 9, r = g & 7, i = (g >> 3) & 63;
    int cL = l & 15, gq = l >> 4;
    int mBase = 3*w;
    size_t brb = (size_t)(b*RR + r)*HH*NN;
    const float* wrt = wr_t   + brb;
    const float* nrt = ner0_t + brb;
    const float* wst = ws_t   + brb;
    const float* nst = nes0_t + brb;
    __shared__ __align__(16) unsigned sB[3072];

    // C init: ner0' + nes0 (this wave's feats)
    f32x4 acc[3][4];
    #pragma unroll
    for (int mi=0;mi<3;mi++)
      #pragma unroll
      for (int q=0;q<4;q++){
        int c = 16*(mBase+mi) + 4*gq + q;
        float nr = nrt[c*NN + i];
        #pragma unroll
        for (int n=0;n<4;n++) acc[mi][n][q] = nr + nst[c*NN + 16*n + cL];
      }

    // GEMM1: t0 = Ee0^T @ edge_enc^T  (B built per kb)
    #pragma unroll
    for (int kb=0;kb<3;kb++){
        u32x4 Bk[4];
        build_ee_kb(Bk, wrt, wst, i, kb, gq, cL);
        egemm_kb(acc, pk_e + PE_EE0, mBase, kb, l, Bk);
    }
    repack_half(acc, sB, mBase, gq, cL);
    __syncthreads();

    // GEMM2: ee0 = W20^T @ t0^T
    einit_b(acc, ep0_b2, mBase, gq);
    #pragma unroll
    for (int kb=0;kb<3;kb++){
        u32x4 Bk[4];
        load_sB_kb(Bk, sB, kb, l);
        egemm_kb(acc, pk_e + PE_W20, mBase, kb, l, Bk);
    }
    #pragma unroll
    for (int mi=0;mi<3;mi++)
      #pragma unroll
      for (int n=0;n<4;n++)
        #pragma unroll
        for (int q=0;q<4;q++) acc[mi][n][q] = fmaxf(acc[mi][n][q], 0.f);

    // store ee0 frags (B-layout bf16, this wave's half) + agg reduce
    unsigned* eo = ee0f + (size_t)g*3072;
    #pragma unroll
    for (int mi=0;mi<3;mi++){
      int m = mBase+mi;
      #pragma unroll
      for (int n=0;n<4;n++){
        int gd = 2*(m&1) + (gq>>1);
        int dw = (((m>>1)*4 + n)*64 + 16*gd + cL)*4 + 2*(gq&1);
        eo[dw]   = pk2(acc[mi][n][0], acc[mi][n][1]);
        eo[dw+1] = pk2(acc[mi][n][2], acc[mi][n][3]);
      }
    }
    #pragma unroll
    for (int mi=0;mi<3;mi++)
      #pragma unroll
      for (int q=0;q<4;q++){
        float s = acc[mi][0][q] + acc[mi][1][q] + acc[mi][2][q] + acc[mi][3][q];
        s += __shfl_xor(s, 1);
        s += __shfl_xor(s, 2);
        s += __shfl_xor(s, 4);
        s += __shfl_xor(s, 8);
        if (cL == 0) agg_t[brb + (16*(mBase+mi) + 4*gq + q)*NN + i] = s;
      }
}

// ---------------------------------------------------------------------------
// K3: node update + step-1 projections via split-MFMA. grid 128 x 64.
// ---------------------------------------------------------------------------
__global__ __launch_bounds__(64)
void k3_node(const float* __restrict__ enc_t_g, const float* __restrict__ agg_t_g,
             const float* __restrict__ np_b1, const float* __restrict__ np_b2,
             const float* __restrict__ ep1_b1,
             const unsigned* __restrict__ pk_n,
             float* __restrict__ ner1_t, float* __restrict__ nes1_t)
{
    int blk = blockIdx.x, l = threadIdx.x;
    int br = blk >> 2, chunk = blk & 3;
    int cL = l & 15, gq = l >> 4;
    int col = 16*chunk + cL;
    __shared__ __align__(16) float sF[HH*LSTR];
    size_t brb = (size_t)br * HH * NN;
    const float* enc_t = enc_t_g + brb;
    const float* agg_t = agg_t_g + brb;

    f32x4 acc[6];

    // t = relu(enc @ Wn12 + agg @ Wn3 + np_b1)
    cinit6(acc, np_b1, gq);
    gemm96_glb(acc, pk_n+PN_WN12, pk_n+PN_WN12+4608, l, gq, col, enc_t);
    gemm96_glb(acc, pk_n+PN_WN3,  pk_n+PN_WN3+4608,  l, gq, col, agg_t);
    relu6(acc);
    accToLds(acc, sF, gq, cL);
    __syncthreads();

    // ne1 = relu(t @ npW2 + np_b2)
    cinit6(acc, np_b2, gq);
    gemm96_lds(acc, pk_n+PN_NPW2, pk_n+PN_NPW2+4608, l, gq, cL, sF);
    relu6(acc);
    __syncthreads();                 // drain reads of t before overwrite
    accToLds(acc, sF, gq, cL);
    __syncthreads();

    // ner1 = ne1 @ Er1 + ep1_b1
    cinit6(acc, ep1_b1, gq);
    gemm96_lds(acc, pk_n+PN_ER1, pk_n+PN_ER1+4608, l, gq, cL, sF);
    storeT16(acc, ner1_t + brb, gq, col);

    // nes1 = ne1 @ Es1
    cinit6z(acc);
    gemm96_lds(acc, pk_n+PN_ES1, pk_n+PN_ES1+4608, l, gq, cL, sF);
    storeT16(acc, nes1_t + brb, gq, col);
}

// ---------------------------------------------------------------------------
// K4: edge prop step 1 + prediction head via MFMA. block = 128 (2 waves),
// wave w owns m-tiles 3w..3w+2; barriers guard LDS B-frag handoffs.
// ---------------------------------------------------------------------------
__global__ __launch_bounds__(128)
void k4_edge1(const float* __restrict__ wr_t, const float* __restrict__ ws_t,
              const float* __restrict__ ner1_t, const float* __restrict__ nes1_t,
              const unsigned* __restrict__ pk_e,
              const unsigned* __restrict__ ee0f,
              const float* __restrict__ ep1_b2,
              const float* __restrict__ pred_b1, const float* __restrict__ pred_b2,
              float* __restrict__ out)
{
    int g = blockIdx.x, tid = threadIdx.x;
    int w = tid >> 6, l = tid & 63;
    int b = g >> 9, i = (g >> 3) & 63, r = g & 7;
    int cL = l & 15, gq = l >> 4;
    int mBase = 3*w;
    size_t brb = (size_t)(b*RR + r)*HH*NN;
    const float* wrt = wr_t   + brb;
    const float* wst = ws_t   + brb;
    const float* nrt = ner1_t + brb;
    const float* nst = nes1_t + brb;
    __shared__ __align__(16) unsigned sB[3072];

    const u32x4* e0p = (const u32x4*)ee0f + (size_t)g*768;

    // C init: ner1' + nes1
    f32x4 acc[3][4];
    #pragma unroll
    for (int mi=0;mi<3;mi++)
      #pragma unroll
      for (int q=0;q<4;q++){
        int c = 16*(mBase+mi) + 4*gq + q;
        float nr = nrt[c*NN + i];
        #pragma unroll
        for (int n=0;n<4;n++) acc[mi][n][q] = nr + nst[c*NN + 16*n + cL];
      }

    // GEMM1: t1 = Ee1^T @ ee0^T  (B loaded per kb from global frag store)
    #pragma unroll
    for (int kb=0;kb<3;kb++){
        u32x4 Bk[4];
        #pragma unroll
        for (int n=0;n<4;n++) Bk[n] = e0p[(kb*4+n)*64 + l];
        egemm_kb(acc, pk_e + PE_EE1, mBase, kb, l, Bk);
    }
    repack_half(acc, sB, mBase, gq, cL);         // t1 -> sB
    __syncthreads();

    // GEMM2: ee1 = W21^T @ t1^T
    einit_b(acc, ep1_b2, mBase, gq);
    #pragma unroll
    for (int kb=0;kb<3;kb++){
        u32x4 Bk[4];
        load_sB_kb(Bk, sB, kb, l);
        egemm_kb(acc, pk_e + PE_W21, mBase, kb, l, Bk);
    }
    __syncthreads();                             // drain t1 reads
    repack_half(acc, sB, mBase, gq, cL);         // ee1 -> sB
    __syncthreads();

    // GEMM3: tp = pred_b1 + Pe^T @ ee1^T
    einit_b(acc, pred_b1, mBase, gq);
    #pragma unroll
    for (int kb=0;kb<3;kb++){
        u32x4 Bk[4];
        load_sB_kb(Bk, sB, kb, l);
        egemm_kb(acc, pk_e + PE_PE, mBase, kb, l, Bk);
    }
    __syncthreads();                             // drain ee1 reads

    // GEMM4: tp += Pc^T @ edge_enc^T (B rebuilt per kb, registers only)
    #pragma unroll
    for (int kb=0;kb<3;kb++){
        u32x4 Bk[4];
        build_ee_kb(Bk, wrt, wst, i, kb, gq, cL);
        egemm_kb(acc, pk_e + PE_PC, mBase, kb, l, Bk);
    }
    repack_half(acc, sB, mBase, gq, cL);         // tp -> sB
    __syncthreads();

    // GEMM5: out = P2^T @ tp^T (rows 0,1 valid); wave w handles n = 2w, 2w+1
    f32x4 c5[2];
    #pragma unroll
    for (int nn=0;nn<2;nn++){
        c5[nn][0] = (gq == 0) ? pred_b2[0] : 0.f;
        c5[nn][1] = (gq == 0) ? pred_b2[1] : 0.f;
        c5[nn][2] = 0.f; c5[nn][3] = 0.f;
    }
    #pragma unroll
    for (int kb=0;kb<3;kb++){
        bf16x8 A2 = __builtin_bit_cast(bf16x8, *(const u32x4*)&pk_e[PE_P2*1 + (kb*64 + l)*4]);
        #pragma unroll
        for (int nn=0;nn<2;nn++){
            int n = 2*w + nn;
            bf16x8 Bf = __builtin_bit_cast(bf16x8, *(const u32x4*)&sB[((kb*4+n)*64 + l)*4]);
            c5[nn] = MFMA16(A2, Bf, c5[nn]);
        }
    }
    if (gq == 0) {
        float2* o2 = (float2*)out;
        #pragma unroll
        for (int nn=0;nn<2;nn++){
            size_t j = 16*(2*w+nn) + cL;
            o2[(((size_t)(b*NN + i))*NN + j)*RR + r] = make_float2(c5[nn][0], c5[nn][1]);
        }
    }
}

// ---------------------------------------------------------------------------
extern "C" void kernel_launch(void* const* d_in, const int* in_sizes, int n_in,
                              void* d_out, int out_size, void* d_ws, size_t ws_size,
                              hipStream_t stream)
{
    const float* node_rep = (const float*)d_in[0];
    const float* ne_W    = (const float*)d_in[1];
    const float* ne_b    = (const float*)d_in[2];
    const float* ee_W    = (const float*)d_in[3];
    const float* ee_b    = (const float*)d_in[4];
    const float* np_W1   = (const float*)d_in[5];
    const float* np_b1   = (const float*)d_in[6];
    const float* np_W2   = (const float*)d_in[7];
    const float* np_b2   = (const float*)d_in[8];
    const float* ep0_W1  = (const float*)d_in[9];
    const float* ep0_b1  = (const float*)d_in[10];
    const float* ep0_W2  = (const float*)d_in[11];
    const float* ep0_b2  = (const float*)d_in[12];
    const float* ep1_W1  = (const float*)d_in[13];
    const float* ep1_b1  = (const float*)d_in[14];
    const float* ep1_W2  = (const float*)d_in[15];
    const float* ep1_b2  = (const float*)d_in[16];
    const float* pred_W1 = (const float*)d_in[17];
    const float* pred_b1 = (const float*)d_in[18];
    const float* pred_W2 = (const float*)d_in[19];
    const float* pred_b2 = (const float*)d_in[20];
    float* wsf = (float*)d_ws;
    float* out = (float*)d_out;

    float* wr_t   = wsf + OFF_WR_T;
    float* ws_t   = wsf + OFF_WS_T;
    float* ner0_t = wsf + OFF_NER0;
    float* nes0_t = wsf + OFF_NES0;
    float* ner1_t = wsf + OFF_NER1;
    float* nes1_t = wsf + OFF_NES1;
    float* enc_t  = wsf + OFF_ENCT;
    float* agg_t  = wsf + OFF_AGGT;
    unsigned* pk_e = (unsigned*)(wsf + OFF_PKE);
    unsigned* pk_n = (unsigned*)(wsf + OFF_PKN);
    unsigned* ee0f = (unsigned*)(wsf + OFF_EE0F);

    k0_pack<<<255, 64, 0, stream>>>(ne_W, ee_W, ep0_W1, ep0_W2, ep1_W1, ep1_W2,
                                    np_W1, np_W2, pred_W1, pred_W2, pk_e, pk_n);

    k1_node<<<128, 64, 0, stream>>>(node_rep, ne_b, ee_b, ep0_b1, pk_n,
                                    wr_t, ws_t, ner0_t, nes0_t, enc_t);

    k2_edge0<<<NGROUP, 128, 0, stream>>>(wr_t, ws_t, ner0_t, nes0_t, pk_e, ep0_b2,
                                         ee0f, agg_t);

    k3_node<<<128, 64, 0, stream>>>(enc_t, agg_t, np_b1, np_b2, ep1_b1, pk_n,
                                    ner1_t, nes1_t);

    k4_edge1<<<NGROUP, 128, 0, stream>>>(wr_t, ws_t, ner1_t, nes1_t, pk_e, ee0f,
                                         ep1_b2, pred_b1, pred_b2, out);
}

// Round 9
// 68.730 us; speedup vs baseline: 10.8097x; 1.4424x over previous
//
#include <hip/hip_runtime.h>
#include <hip/hip_bf16.h>

#define BB 4
#define NN 64
#define RR 8
#define DD 32
#define HH 96
#define NGROUP (BB*NN*RR)   // 2048
#define LSTR 17             // padded LDS stride (floats) for node repack buffer

// workspace float offsets — all node-side tensors transposed [b*8+r][feat][node]
#define OFF_WR_T  0
#define OFF_WS_T  196608
#define OFF_NER0  393216
#define OFF_NES0  589824
#define OFF_NER1  786432
#define OFF_NES1  983040
#define OFF_ENCT  1179648
#define OFF_AGGT  1376256
#define OFF_PKE   1572864      // edge-side packed weights (hi only), 28416 u32
#define OFF_PKN   1601280      // node-side packed weights (hi+lo), 73728 u32
#define OFF_EE0F  1675008      // ee0 in B-frag bf16 form, 2048*3072 u32

// pk_e u32 offsets (frag = 256 u32; 96x96 mat = 18 frags = 4608)
#define PE_EE0  0
#define PE_W20  4608
#define PE_EE1  9216
#define PE_W21  13824
#define PE_PE   18432
#define PE_PC   23040
#define PE_P2   27648
// pk_n u32 offsets (K=32 mats: 6 frags = 1536/part; K=96 mats: 4608/part; hi then lo)
#define PN_NEW  0
#define PN_WR   3072
#define PN_WS   6144
#define PN_ER0  9216
#define PN_ES0  18432
#define PN_WN12 27648
#define PN_WN3  36864
#define PN_NPW2 46080
#define PN_ER1  55296
#define PN_ES1  64512

typedef __attribute__((ext_vector_type(4))) float f32x4;
typedef __attribute__((ext_vector_type(8))) short bf16x8;
typedef __attribute__((ext_vector_type(4))) unsigned int u32x4;

__device__ __forceinline__ unsigned int pk2(float lo, float hi){
    unsigned short a = __builtin_bit_cast(unsigned short, __float2bfloat16(lo));
    unsigned short b = __builtin_bit_cast(unsigned short, __float2bfloat16(hi));
    return (unsigned)a | ((unsigned)b << 16);
}
// split v into bf16 hi + bf16 lo residual (x ~ hi + lo to ~2^-17 rel)
__device__ __forceinline__ void split2(float v0, float v1, unsigned &h, unsigned &lo){
    float h0 = __bfloat162float(__float2bfloat16(v0));
    float h1 = __bfloat162float(__float2bfloat16(v1));
    h  = pk2(v0, v1);
    lo = pk2(v0 - h0, v1 - h1);
}

#define MFMA16(A,B,C) __builtin_amdgcn_mfma_f32_16x16x32_bf16((A),(B),(C),0,0,0)

// ============ node-kernel helpers: 1 m-tile per wave (6 waves/block) ========
// one split-GEMM step on a single m-tile: acc += Ah@Bh + Ah@Bl + Al@Bh
__device__ __forceinline__ void gemm_1m(f32x4 &acc,
    const unsigned* __restrict__ ph, const unsigned* __restrict__ pl,
    int idx, int l, const u32x4 &Bh, const u32x4 &Bl)
{
    bf16x8 bh = __builtin_bit_cast(bf16x8, Bh);
    bf16x8 bl = __builtin_bit_cast(bf16x8, Bl);
    bf16x8 ah = __builtin_bit_cast(bf16x8, *(const u32x4*)&ph[idx*256 + l*4]);
    bf16x8 al = __builtin_bit_cast(bf16x8, *(const u32x4*)&pl[idx*256 + l*4]);
    acc = MFMA16(ah, bh, acc);
    acc = MFMA16(ah, bl, acc);
    acc = MFMA16(al, bh, acc);
}
// build split B-frag for one kb from an LDS fp32 buffer [feat][LSTR]
__device__ __forceinline__ void buildB_lds(const float* sF, int kb, int gq, int cL,
                                           u32x4 &Bh, u32x4 &Bl){
    #pragma unroll
    for (int p=0;p<4;p++){
        int f = 32*kb + 8*gq + 2*p;
        unsigned h, lo;
        split2(sF[f*LSTR + cL], sF[(f+1)*LSTR + cL], h, lo);
        Bh[p] = h; Bl[p] = lo;
    }
}
// K=96 split GEMM (one m-tile) with B from LDS buffer
__device__ __forceinline__ void gemm96_1m(f32x4 &acc,
    const unsigned* __restrict__ ph, const unsigned* __restrict__ pl,
    int w, int l, int gq, int cL, const float* sF)
{
    #pragma unroll
    for (int kb=0;kb<3;kb++){
        u32x4 Bh, Bl;
        buildB_lds(sF, kb, gq, cL, Bh, Bl);
        gemm_1m(acc, ph, pl, w*3+kb, l, Bh, Bl);
    }
}
__device__ __forceinline__ void relu1(f32x4 &acc){
    #pragma unroll
    for (int q=0;q<4;q++) acc[q] = fmaxf(acc[q], 0.f);
}
__device__ __forceinline__ void cinit1(f32x4 &acc, const float* __restrict__ bv, int w, int gq){
    #pragma unroll
    for (int q=0;q<4;q++) acc[q] = bv[16*w+4*gq+q];
}
// store one m-tile transposed to dst[feat][col]
__device__ __forceinline__ void storeT1(const f32x4 &acc, float* __restrict__ dst,
                                        int w, int gq, int col){
    #pragma unroll
    for (int q=0;q<4;q++) dst[(16*w+4*gq+q)*NN + col] = acc[q];
}
// write one m-tile into the LDS repack buffer
__device__ __forceinline__ void toLds1(const f32x4 &acc, float* sF, int w, int gq, int cL){
    #pragma unroll
    for (int q=0;q<4;q++) sF[(16*w+4*gq+q)*LSTR + cL] = acc[q];
}

// ================= edge-kernel helpers (2 waves/block, 3 m-tiles/wave) ======
__device__ __forceinline__ void einit_b(f32x4 (&acc)[3][4], const float* __restrict__ bv,
                                        int mBase, int gq){
    #pragma unroll
    for (int mi=0;mi<3;mi++)
      #pragma unroll
      for (int q=0;q<4;q++){
        float x = bv[16*(mBase+mi)+4*gq+q];
        #pragma unroll
        for (int n=0;n<4;n++) acc[mi][n][q] = x;
      }
}
__device__ __forceinline__ void egemm_kb(f32x4 (&acc)[3][4],
    const unsigned* __restrict__ Apk, int mBase, int kb, int l, const u32x4 (&Bk)[4])
{
    #pragma unroll
    for (int mi=0;mi<3;mi++){
        bf16x8 a = __builtin_bit_cast(bf16x8, *(const u32x4*)&Apk[(((mBase+mi)*3+kb)*64 + l)*4]);
        #pragma unroll
        for (int n=0;n<4;n++){
            bf16x8 bf = __builtin_bit_cast(bf16x8, Bk[n]);
            acc[mi][n] = MFMA16(a, bf, acc[mi][n]);
        }
    }
}
__device__ __forceinline__ void build_ee_kb(u32x4 (&Bk)[4],
    const float* __restrict__ wrt, const float* __restrict__ wst,
    int i, int kb, int gq, int cL)
{
    #pragma unroll
    for (int n=0;n<4;n++)
      #pragma unroll
      for (int p=0;p<4;p++){
        int h = 32*kb + 8*gq + 2*p;
        int j = 16*n + cL;
        float a0 = fmaxf(wrt[h*NN + i]     + wst[h*NN + j],     0.f);
        float a1 = fmaxf(wrt[(h+1)*NN + i] + wst[(h+1)*NN + j], 0.f);
        Bk[n][p] = pk2(a0, a1);
      }
}
__device__ __forceinline__ void load_sB_kb(u32x4 (&Bk)[4], const unsigned* sB, int kb, int l){
    #pragma unroll
    for (int n=0;n<4;n++) Bk[n] = *(const u32x4*)&sB[((kb*4+n)*64 + l)*4];
}
__device__ __forceinline__ void repack_half(const f32x4 (&acc)[3][4], unsigned* sB,
                                            int mBase, int gq, int cL)
{
    #pragma unroll
    for (int mi=0;mi<3;mi++){
      int m = mBase+mi;
      #pragma unroll
      for (int n=0;n<4;n++){
        float v0 = fmaxf(acc[mi][n][0],0.f), v1 = fmaxf(acc[mi][n][1],0.f);
        float v2 = fmaxf(acc[mi][n][2],0.f), v3 = fmaxf(acc[mi][n][3],0.f);
        int gd = 2*(m&1) + (gq>>1);
        int dw = (((m>>1)*4 + n)*64 + 16*gd + cL)*4 + 2*(gq&1);
        sB[dw]   = pk2(v0,v1);
        sB[dw+1] = pk2(v2,v3);
      }
    }
}

// ---------------------------------------------------------------------------
// K0: pack all weights into MFMA A-frags. grid 255 x 64. (unchanged)
// ---------------------------------------------------------------------------
__global__ __launch_bounds__(64)
void k0_pack(const float* __restrict__ ne_W, const float* __restrict__ ee_W,
             const float* __restrict__ ep0_W1, const float* __restrict__ ep0_W2,
             const float* __restrict__ ep1_W1, const float* __restrict__ ep1_W2,
             const float* __restrict__ np_W1, const float* __restrict__ np_W2,
             const float* __restrict__ pred_W1, const float* __restrict__ pred_W2,
             unsigned* __restrict__ pk_e, unsigned* __restrict__ pk_n)
{
    int t = blockIdx.x, l = threadIdx.x;
    int cL = l & 15, gq = l >> 4;
    if (t < 108) {                         // edge-side, hi only
        int mat = t/18, tt = t%18, mt = tt/3, kb = tt%3;
        const float* mats[6] = { ep0_W1 + 2*HH*HH, ep0_W2, ep1_W1 + 2*HH*HH,
                                 ep1_W2, pred_W1, pred_W1 + HH*HH };
        const float* src = mats[mat];
        u32x4 d;
        #pragma unroll
        for (int p=0;p<4;p++){
            int k = 32*kb + 8*gq + 2*p;
            d[p] = pk2(src[k*HH + 16*mt + cL], src[(k+1)*HH + 16*mt + cL]);
        }
        *(u32x4*)&pk_e[mat*4608 + (mt*3+kb)*256 + l*4] = d;
    } else if (t < 111) {                  // pred_W2 zero-padded to 16 cols
        int kb = t - 108;
        u32x4 d;
        #pragma unroll
        for (int p=0;p<4;p++){
            int k = 32*kb + 8*gq + 2*p;
            float lo = (cL < 2) ? pred_W2[k*2 + cL]     : 0.f;
            float hi = (cL < 2) ? pred_W2[(k+1)*2 + cL] : 0.f;
            d[p] = pk2(lo, hi);
        }
        *(u32x4*)&pk_e[PE_P2 + kb*256 + l*4] = d;
    } else {
        int u = t - 111;
        if (u < 18) {                      // K=32 node mats: neW, Wr, Ws (hi+lo)
            int mat = u/6, mt = u%6;
            const float* srcs[3] = { ne_W, ee_W, ee_W + DD*HH };
            const float* src = srcs[mat];
            u32x4 dh, dl;
            #pragma unroll
            for (int p=0;p<4;p++){
                int k = 8*gq + 2*p;
                unsigned th, tl;
                split2(src[k*HH + 16*mt + cL], src[(k+1)*HH + 16*mt + cL], th, tl);
                dh[p] = th; dl[p] = tl;
            }
            int base = mat*3072 + mt*256 + l*4;
            *(u32x4*)&pk_n[base]        = dh;
            *(u32x4*)&pk_n[base + 1536] = dl;
        } else {                           // K=96 node mats (hi+lo)
            int u2 = u-18, mat = u2/18, tt = u2%18, mt = tt/3, kb = tt%3;
            u32x4 dh, dl;
            #pragma unroll
            for (int p=0;p<4;p++){
                int k = 32*kb + 8*gq + 2*p, col = 16*mt + cL;
                float v0, v1;
                if (mat == 2) {            // Wn12 = Wn1 + Wn2
                    v0 = np_W1[k*HH+col]     + np_W1[(HH+k)*HH+col];
                    v1 = np_W1[(k+1)*HH+col] + np_W1[(HH+k+1)*HH+col];
                } else {
                    const float* src = (mat==0) ? ep0_W1
                                     : (mat==1) ? ep0_W1 + HH*HH
                                     : (mat==3) ? np_W1 + 2*HH*HH
                                     : (mat==4) ? np_W2
                                     : (mat==5) ? ep1_W1
                                     :            ep1_W1 + HH*HH;
                    v0 = src[k*HH+col]; v1 = src[(k+1)*HH+col];
                }
                unsigned th, tl;
                split2(v0, v1, th, tl);
                dh[p] = th; dl[p] = tl;
            }
            int base = PN_ER0 + mat*9216 + (mt*3+kb)*256 + l*4;
            *(u32x4*)&pk_n[base]        = dh;
            *(u32x4*)&pk_n[base + 4608] = dl;
        }
    }
}

// ---------------------------------------------------------------------------
// K1: node encode + step-0 projections. grid 128 x 384 (6 waves, 1 m-tile/wave).
// Cooperative LDS staging of the node_rep chunk; LDS repack between stages.
// ---------------------------------------------------------------------------
__global__ __launch_bounds__(384)
void k1_node(const float* __restrict__ node_rep,
             const float* __restrict__ ne_b, const float* __restrict__ ee_b,
             const float* __restrict__ ep0_b1,
             const unsigned* __restrict__ pk_n,
             float* __restrict__ wr_t, float* __restrict__ ws_t,
             float* __restrict__ ner0_t, float* __restrict__ nes0_t,
             float* __restrict__ enc_t)
{
    int blk = blockIdx.x, tid = threadIdx.x;
    int br = blk >> 2, chunk = blk & 3;
    int b = br >> 3, r = br & 7;
    int w = tid >> 6, l = tid & 63;
    int cL = l & 15, gq = l >> 4;
    int col = 16*chunk + cL;
    __shared__ float sN[DD*16];                    // node chunk [32 feats][16 cols]
    __shared__ __align__(16) float sF[HH*LSTR];    // repack buffer [96][17]
    size_t brb = (size_t)br * HH * NN;

    // coop stage: node_rep rows (b, 16*chunk+row, r) -> sN[k][row]
    for (int idx = tid; idx < 512; idx += 384){
        int row = idx >> 5, k = idx & 31;
        sN[k*16 + row] = node_rep[((size_t)((b*NN + 16*chunk + row)*RR + r))*DD + k];
    }
    __syncthreads();

    // node B-frag (K=32) from LDS
    u32x4 nBh, nBl;
    #pragma unroll
    for (int p=0;p<4;p++){
        int k = 8*gq + 2*p;
        unsigned h, lo;
        split2(sN[k*16 + cL], sN[(k+1)*16 + cL], h, lo);
        nBh[p] = h; nBl[p] = lo;
    }

    f32x4 acc;

    // enc = relu(node @ neW + ne_b)   (wave w -> m-tile w)
    cinit1(acc, ne_b, w, gq);
    gemm_1m(acc, pk_n+PN_NEW, pk_n+PN_NEW+1536, w, l, nBh, nBl);
    relu1(acc);
    storeT1(acc, enc_t + brb, w, gq, col);
    toLds1(acc, sF, w, gq, cL);
    __syncthreads();

    // ner0 = enc @ Er0 + ep0_b1
    cinit1(acc, ep0_b1, w, gq);
    gemm96_1m(acc, pk_n+PN_ER0, pk_n+PN_ER0+4608, w, l, gq, cL, sF);
    storeT1(acc, ner0_t + brb, w, gq, col);

    // nes0 = enc @ Es0
    #pragma unroll
    for (int q=0;q<4;q++) acc[q] = 0.f;
    gemm96_1m(acc, pk_n+PN_ES0, pk_n+PN_ES0+4608, w, l, gq, cL, sF);
    storeT1(acc, nes0_t + brb, w, gq, col);

    // wr' = node @ Wr + ee_b
    cinit1(acc, ee_b, w, gq);
    gemm_1m(acc, pk_n+PN_WR, pk_n+PN_WR+1536, w, l, nBh, nBl);
    storeT1(acc, wr_t + brb, w, gq, col);

    // ws = node @ Ws
    #pragma unroll
    for (int q=0;q<4;q++) acc[q] = 0.f;
    gemm_1m(acc, pk_n+PN_WS, pk_n+PN_WS+1536, w, l, nBh, nBl);
    storeT1(acc, ws_t + brb, w, gq, col);
}

// ---------------------------------------------------------------------------
// K2: edge prop step 0 via MFMA. block = 128 (2 waves), 3 m-tiles/wave. (unchanged)
// ---------------------------------------------------------------------------
__global__ __launch_bounds__(128)
void k2_edge0(const float* __restrict__ wr_t, const float* __restrict__ ws_t,
              const float* __restrict__ ner0_t, const float* __restrict__ nes0_t,
              const unsigned* __restrict__ pk_e,
              const float* __restrict__ ep0_b2,
              unsigned* __restrict__ ee0f, float* __restrict__ agg_t)
{
    int g = blockIdx.x, tid = threadIdx.x;
    int w = tid >> 6, l = tid & 63;
    int b = g >> 9, r = g & 7, i = (g >> 3) & 63;
    int cL = l & 15, gq = l >> 4;
    int mBase = 3*w;
    size_t brb = (size_t)(b*RR + r)*HH*NN;
    const float* wrt = wr_t   + brb;
    const float* nrt = ner0_t + brb;
    const float* wst = ws_t   + brb;
    const float* nst = nes0_t + brb;
    __shared__ __align__(16) unsigned sB[3072];

    f32x4 acc[3][4];
    #pragma unroll
    for (int mi=0;mi<3;mi++)
      #pragma unroll
      for (int q=0;q<4;q++){
        int c = 16*(mBase+mi) + 4*gq + q;
        float nr = nrt[c*NN + i];
        #pragma unroll
        for (int n=0;n<4;n++) acc[mi][n][q] = nr + nst[c*NN + 16*n + cL];
      }

    // GEMM1: t0 = Ee0^T @ edge_enc^T
    #pragma unroll
    for (int kb=0;kb<3;kb++){
        u32x4 Bk[4];
        build_ee_kb(Bk, wrt, wst, i, kb, gq, cL);
        egemm_kb(acc, pk_e + PE_EE0, mBase, kb, l, Bk);
    }
    repack_half(acc, sB, mBase, gq, cL);
    __syncthreads();

    // GEMM2: ee0 = W20^T @ t0^T
    einit_b(acc, ep0_b2, mBase, gq);
    #pragma unroll
    for (int kb=0;kb<3;kb++){
        u32x4 Bk[4];
        load_sB_kb(Bk, sB, kb, l);
        egemm_kb(acc, pk_e + PE_W20, mBase, kb, l, Bk);
    }
    #pragma unroll
    for (int mi=0;mi<3;mi++)
      #pragma unroll
      for (int n=0;n<4;n++)
        #pragma unroll
        for (int q=0;q<4;q++) acc[mi][n][q] = fmaxf(acc[mi][n][q], 0.f);

    unsigned* eo = ee0f + (size_t)g*3072;
    #pragma unroll
    for (int mi=0;mi<3;mi++){
      int m = mBase+mi;
      #pragma unroll
      for (int n=0;n<4;n++){
        int gd = 2*(m&1) + (gq>>1);
        int dw = (((m>>1)*4 + n)*64 + 16*gd + cL)*4 + 2*(gq&1);
        eo[dw]   = pk2(acc[mi][n][0], acc[mi][n][1]);
        eo[dw+1] = pk2(acc[mi][n][2], acc[mi][n][3]);
      }
    }
    #pragma unroll
    for (int mi=0;mi<3;mi++)
      #pragma unroll
      for (int q=0;q<4;q++){
        float s = acc[mi][0][q] + acc[mi][1][q] + acc[mi][2][q] + acc[mi][3][q];
        s += __shfl_xor(s, 1);
        s += __shfl_xor(s, 2);
        s += __shfl_xor(s, 4);
        s += __shfl_xor(s, 8);
        if (cL == 0) agg_t[brb + (16*(mBase+mi) + 4*gq + q)*NN + i] = s;
      }
}

// ---------------------------------------------------------------------------
// K3: node update + step-1 projections. grid 128 x 384 (6 waves, 1 m-tile/wave).
// Cooperative LDS staging of enc/agg chunks; LDS repack between stages.
// ---------------------------------------------------------------------------
__global__ __launch_bounds__(384)
void k3_node(const float* __restrict__ enc_t_g, const float* __restrict__ agg_t_g,
             const float* __restrict__ np_b1, const float* __restrict__ np_b2,
             const float* __restrict__ ep1_b1,
             const unsigned* __restrict__ pk_n,
             float* __restrict__ ner1_t, float* __restrict__ nes1_t)
{
    int blk = blockIdx.x, tid = threadIdx.x;
    int br = blk >> 2, chunk = blk & 3;
    int w = tid >> 6, l = tid & 63;
    int cL = l & 15, gq = l >> 4;
    int col = 16*chunk + cL;
    __shared__ __align__(16) float sE[HH*LSTR], sA[HH*LSTR], sF[HH*LSTR];
    size_t brb = (size_t)br * HH * NN;
    const float* enc_t = enc_t_g + brb;
    const float* agg_t = agg_t_g + brb;

    // coop stage: enc/agg chunk [96 feats][16 cols] -> sE/sA
    for (int idx = tid; idx < HH*16; idx += 384){
        int f = idx >> 4, c = idx & 15;
        sE[f*LSTR + c] = enc_t[f*NN + 16*chunk + c];
        sA[f*LSTR + c] = agg_t[f*NN + 16*chunk + c];
    }
    __syncthreads();

    f32x4 acc;

    // t = relu(enc @ Wn12 + agg @ Wn3 + np_b1)
    cinit1(acc, np_b1, w, gq);
    gemm96_1m(acc, pk_n+PN_WN12, pk_n+PN_WN12+4608, w, l, gq, cL, sE);
    gemm96_1m(acc, pk_n+PN_WN3,  pk_n+PN_WN3+4608,  w, l, gq, cL, sA);
    relu1(acc);
    toLds1(acc, sF, w, gq, cL);
    __syncthreads();

    // ne1 = relu(t @ npW2 + np_b2)
    cinit1(acc, np_b2, w, gq);
    gemm96_1m(acc, pk_n+PN_NPW2, pk_n+PN_NPW2+4608, w, l, gq, cL, sF);
    relu1(acc);
    __syncthreads();                 // drain reads of t before overwrite
    toLds1(acc, sF, w, gq, cL);
    __syncthreads();

    // ner1 = ne1 @ Er1 + ep1_b1
    cinit1(acc, ep1_b1, w, gq);
    gemm96_1m(acc, pk_n+PN_ER1, pk_n+PN_ER1+4608, w, l, gq, cL, sF);
    storeT1(acc, ner1_t + brb, w, gq, col);

    // nes1 = ne1 @ Es1
    #pragma unroll
    for (int q=0;q<4;q++) acc[q] = 0.f;
    gemm96_1m(acc, pk_n+PN_ES1, pk_n+PN_ES1+4608, w, l, gq, cL, sF);
    storeT1(acc, nes1_t + brb, w, gq, col);
}

// ---------------------------------------------------------------------------
// K4: edge prop step 1 + prediction head via MFMA. block = 128 (2 waves). (unchanged)
// ---------------------------------------------------------------------------
__global__ __launch_bounds__(128)
void k4_edge1(const float* __restrict__ wr_t, const float* __restrict__ ws_t,
              const float* __restrict__ ner1_t, const float* __restrict__ nes1_t,
              const unsigned* __restrict__ pk_e,
              const unsigned* __restrict__ ee0f,
              const float* __restrict__ ep1_b2,
              const float* __restrict__ pred_b1, const float* __restrict__ pred_b2,
              float* __restrict__ out)
{
    int g = blockIdx.x, tid = threadIdx.x;
    int w = tid >> 6, l = tid & 63;
    int b = g >> 9, i = (g >> 3) & 63, r = g & 7;
    int cL = l & 15, gq = l >> 4;
    int mBase = 3*w;
    size_t brb = (size_t)(b*RR + r)*HH*NN;
    const float* wrt = wr_t   + brb;
    const float* wst = ws_t   + brb;
    const float* nrt = ner1_t + brb;
    const float* nst = nes1_t + brb;
    __shared__ __align__(16) unsigned sB[3072];

    const u32x4* e0p = (const u32x4*)ee0f + (size_t)g*768;

    f32x4 acc[3][4];
    #pragma unroll
    for (int mi=0;mi<3;mi++)
      #pragma unroll
      for (int q=0;q<4;q++){
        int c = 16*(mBase+mi) + 4*gq + q;
        float nr = nrt[c*NN + i];
        #pragma unroll
        for (int n=0;n<4;n++) acc[mi][n][q] = nr + nst[c*NN + 16*n + cL];
      }

    // GEMM1: t1 = Ee1^T @ ee0^T
    #pragma unroll
    for (int kb=0;kb<3;kb++){
        u32x4 Bk[4];
        #pragma unroll
        for (int n=0;n<4;n++) Bk[n] = e0p[(kb*4+n)*64 + l];
        egemm_kb(acc, pk_e + PE_EE1, mBase, kb, l, Bk);
    }
    repack_half(acc, sB, mBase, gq, cL);         // t1 -> sB
    __syncthreads();

    // GEMM2: ee1 = W21^T @ t1^T
    einit_b(acc, ep1_b2, mBase, gq);
    #pragma unroll
    for (int kb=0;kb<3;kb++){
        u32x4 Bk[4];
        load_sB_kb(Bk, sB, kb, l);
        egemm_kb(acc, pk_e + PE_W21, mBase, kb, l, Bk);
    }
    __syncthreads();                             // drain t1 reads
    repack_half(acc, sB, mBase, gq, cL);         // ee1 -> sB
    __syncthreads();

    // GEMM3: tp = pred_b1 + Pe^T @ ee1^T
    einit_b(acc, pred_b1, mBase, gq);
    #pragma unroll
    for (int kb=0;kb<3;kb++){
        u32x4 Bk[4];
        load_sB_kb(Bk, sB, kb, l);
        egemm_kb(acc, pk_e + PE_PE, mBase, kb, l, Bk);
    }
    __syncthreads();                             // drain ee1 reads

    // GEMM4: tp += Pc^T @ edge_enc^T
    #pragma unroll
    for (int kb=0;kb<3;kb++){
        u32x4 Bk[4];
        build_ee_kb(Bk, wrt, wst, i, kb, gq, cL);
        egemm_kb(acc, pk_e + PE_PC, mBase, kb, l, Bk);
    }
    repack_half(acc, sB, mBase, gq, cL);         // tp -> sB
    __syncthreads();

    // GEMM5: out = P2^T @ tp^T (rows 0,1 valid); wave w handles n = 2w, 2w+1
    f32x4 c5[2];
    #pragma unroll
    for (int nn=0;nn<2;nn++){
        c5[nn][0] = (gq == 0) ? pred_b2[0] : 0.f;
        c5[nn][1] = (gq == 0) ? pred_b2[1] : 0.f;
        c5[nn][2] = 0.f; c5[nn][3] = 0.f;
    }
    #pragma unroll
    for (int kb=0;kb<3;kb++){
        bf16x8 A2 = __builtin_bit_cast(bf16x8, *(const u32x4*)&pk_e[PE_P2 + (kb*64 + l)*4]);
        #pragma unroll
        for (int nn=0;nn<2;nn++){
            int n = 2*w + nn;
            bf16x8 Bf = __builtin_bit_cast(bf16x8, *(const u32x4*)&sB[((kb*4+n)*64 + l)*4]);
            c5[nn] = MFMA16(A2, Bf, c5[nn]);
        }
    }
    if (gq == 0) {
        float2* o2 = (float2*)out;
        #pragma unroll
        for (int nn=0;nn<2;nn++){
            size_t j = 16*(2*w+nn) + cL;
            o2[(((size_t)(b*NN + i))*NN + j)*RR + r] = make_float2(c5[nn][0], c5[nn][1]);
        }
    }
}

// ---------------------------------------------------------------------------
extern "C" void kernel_launch(void* const* d_in, const int* in_sizes, int n_in,
                              void* d_out, int out_size, void* d_ws, size_t ws_size,
                              hipStream_t stream)
{
    const float* node_rep = (const float*)d_in[0];
    const float* ne_W    = (const float*)d_in[1];
    const float* ne_b    = (const float*)d_in[2];
    const float* ee_W    = (const float*)d_in[3];
    const float* ee_b    = (const float*)d_in[4];
    const float* np_W1   = (const float*)d_in[5];
    const float* np_b1   = (const float*)d_in[6];
    const float* np_W2   = (const float*)d_in[7];
    const float* np_b2   = (const float*)d_in[8];
    const float* ep0_W1  = (const float*)d_in[9];
    const float* ep0_b1  = (const float*)d_in[10];
    const float* ep0_W2  = (const float*)d_in[11];
    const float* ep0_b2  = (const float*)d_in[12];
    const float* ep1_W1  = (const float*)d_in[13];
    const float* ep1_b1  = (const float*)d_in[14];
    const float* ep1_W2  = (const float*)d_in[15];
    const float* ep1_b2  = (const float*)d_in[16];
    const float* pred_W1 = (const float*)d_in[17];
    const float* pred_b1 = (const float*)d_in[18];
    const float* pred_W2 = (const float*)d_in[19];
    const float* pred_b2 = (const float*)d_in[20];
    float* wsf = (float*)d_ws;
    float* out = (float*)d_out;

    float* wr_t   = wsf + OFF_WR_T;
    float* ws_t   = wsf + OFF_WS_T;
    float* ner0_t = wsf + OFF_NER0;
    float* nes0_t = wsf + OFF_NES0;
    float* ner1_t = wsf + OFF_NER1;
    float* nes1_t = wsf + OFF_NES1;
    float* enc_t  = wsf + OFF_ENCT;
    float* agg_t  = wsf + OFF_AGGT;
    unsigned* pk_e = (unsigned*)(wsf + OFF_PKE);
    unsigned* pk_n = (unsigned*)(wsf + OFF_PKN);
    unsigned* ee0f = (unsigned*)(wsf + OFF_EE0F);

    k0_pack<<<255, 64, 0, stream>>>(ne_W, ee_W, ep0_W1, ep0_W2, ep1_W1, ep1_W2,
                                    np_W1, np_W2, pred_W1, pred_W2, pk_e, pk_n);

    k1_node<<<128, 384, 0, stream>>>(node_rep, ne_b, ee_b, ep0_b1, pk_n,
                                     wr_t, ws_t, ner0_t, nes0_t, enc_t);

    k2_edge0<<<NGROUP, 128, 0, stream>>>(wr_t, ws_t, ner0_t, nes0_t, pk_e, ep0_b2,
                                         ee0f, agg_t);

    k3_node<<<128, 384, 0, stream>>>(enc_t, agg_t, np_b1, np_b2, ep1_b1, pk_n,
                                     ner1_t, nes1_t);

    k4_edge1<<<NGROUP, 128, 0, stream>>>(wr_t, ws_t, ner1_t, nes1_t, pk_e, ee0f,
                                         ep1_b2, pred_b1, pred_b2, out);
}